// Round 10
// baseline (3621.684 us; speedup 1.0000x reference)
//
#include <hip/hip_runtime.h>
#include <cmath>

#define B_   128
#define T_   100
#define IN_  512
#define H_   1024
#define E_   8
#define HH_  512
#define GIN_ 5
#define GH_  8

// LDS layout (bytes): A = weights as bf16 hi/lo MFMA A-frags (16 rows x 1536 k)
// B = 64-k chunk of x|h as bf16 hi/lo B-frags (2 k-tiles x 8 n-tiles)
#define A_HI 0
#define A_LO 49152
#define BB_HI 98304
#define BB_LO 114688
#define LDSZ 131072

typedef unsigned long long u64t;
typedef unsigned int uint32;
typedef __attribute__((ext_vector_type(8))) short bf16x8;
typedef __attribute__((ext_vector_type(4))) float f32x4;

__device__ __forceinline__ float sigf(float x) { return 1.0f / (1.0f + expf(-x)); }

// Agent-scope (sc1) 16B load: bypasses stale per-XCD L2 (fallback tier only).
__device__ __forceinline__ float4 ld_h4_sc1(const float4* p) {
  const u64t* q = (const u64t*)p;
  u64t a = __hip_atomic_load(q,     __ATOMIC_RELAXED, __HIP_MEMORY_SCOPE_AGENT);
  u64t b = __hip_atomic_load(q + 1, __ATOMIC_RELAXED, __HIP_MEMORY_SCOPE_AGENT);
  union { u64t u; float2 f; } ca, cb;
  ca.u = a; cb.u = b;
  return make_float4(ca.f.x, ca.f.y, cb.f.x, cb.f.y);
}

// Grid barrier without cache invalidation (h visibility via sc1 stores +
// fresh/deterministic ring buffers read with plain loads).
__device__ __forceinline__ void gridbar(unsigned* c) {
  __syncthreads();
  if (threadIdx.x == 0) {
    __hip_atomic_fetch_add(c, 1u, __ATOMIC_RELEASE, __HIP_MEMORY_SCOPE_AGENT);
    while (__hip_atomic_load(c, __ATOMIC_RELAXED, __HIP_MEMORY_SCOPE_AGENT) < gridDim.x) {
      __builtin_amdgcn_s_sleep(1);
    }
  }
  __syncthreads();
}

// bf16 round-to-nearest-even via bit arithmetic (no __hip_bfloat162)
__device__ __forceinline__ uint32 bf16_rne(float f) {
  uint32 u = __builtin_bit_cast(uint32, f);
  return (u + 0x7FFFu + ((u >> 16) & 1u)) >> 16;
}

// split f -> bf16 hi (RNE) + bf16 lo (residual), two elements packed per uint
__device__ __forceinline__ void split2(float f0, float f1, uint32& h, uint32& l) {
  uint32 h0 = bf16_rne(f0), h1 = bf16_rne(f1);
  float hf0 = __builtin_bit_cast(float, h0 << 16);
  float hf1 = __builtin_bit_cast(float, h1 << 16);
  uint32 l0 = bf16_rne(f0 - hf0), l1 = bf16_rne(f1 - hf1);
  h = h0 | (h1 << 16);
  l = l0 | (l1 << 16);
}

// B-region byte offset for (k-tile-in-chunk, n-tile, lane) with bank swizzle
__device__ __forceinline__ int boff(int kt, int nt, int lane) {
  return (((((kt << 3) + nt) << 6) + lane) << 4) ^ ((nt & 3) << 5);
}

// Transpose X[b][t][0:512] -> XT4[t][kq][b].
__global__ __launch_bounds__(256) void xt_kernel(
    const float* __restrict__ X, float4* __restrict__ XT4)
{
  int idx = blockIdx.x * 256 + threadIdx.x;     // over 100*128*128
  int b  = idx & 127;
  int kq = (idx >> 7) & 127;
  int t  = idx >> 14;
  XT4[idx] = *(const float4*)(X + ((size_t)b * T_ + t) * IN_ + kq * 4);
}

// Persistent main GRU via bf16-split MFMA (3x mfma_f32_16x16x32_bf16 per k-tile).
// 256 blocks x 1024 threads, 1 block/CU. Block = 4 j-cols; A rows:
//  0-3 reset(x+h), 4-7 update(x+h), 8-11 new-x-only, 12-15 new-h-only.
// Waves = 8 n-tiles x 2 k-slots; C accumulates in regs across all K.
template<bool RING>
__global__ __launch_bounds__(1024, 4) void gru_mfma(
    const float4* __restrict__ XT4, const float* __restrict__ X, int use_xt,
    const float* __restrict__ wih, const float* __restrict__ whh,
    const float* __restrict__ bih, const float* __restrict__ bhh,
    float* __restrict__ ring, unsigned* __restrict__ barr)
{
  extern __shared__ char lds[];
  const int tid  = threadIdx.x;
  const int lane = tid & 63;
  const int wv   = __builtin_amdgcn_readfirstlane(tid >> 6);
  const int nt   = wv & 7;
  const int ktw  = wv >> 3;
  const int j0   = blockIdx.x << 2;

  // ---- one-time: weights -> A fragments (bf16 hi/lo), pairs of k
  for (int ii = tid * 2; ii < 24576; ii += 2048) {
    int r = ii / 1536, k = ii - r * 1536;
    int jj = r & 3, g = r >> 2;
    float f0, f1;
    if (k < IN_) {
      if (g == 3) { f0 = 0.f; f1 = 0.f; }
      else {
        const float* p = wih + (size_t)(((g == 2 ? 2 : g) * H_) + j0 + jj) * IN_ + k;
        f0 = p[0]; f1 = p[1];
      }
    } else {
      if (g == 2) { f0 = 0.f; f1 = 0.f; }
      else {
        const float* p = whh + (size_t)(((g == 3 ? 2 : g) * H_) + j0 + jj) * H_ + (k - IN_);
        f0 = p[0]; f1 = p[1];
      }
    }
    uint32 h, l; split2(f0, f1, h, l);
    int KT = k >> 5, k32 = k & 31;
    int ln  = r + ((k32 >> 3) << 4);
    int off = (KT << 10) + (ln << 4) + ((k32 & 7) << 1);
    *(uint32*)(lds + A_HI + off) = h;
    *(uint32*)(lds + A_LO + off) = l;
  }

  // epilogue biases (threads 0..511: jj x b)
  const int ejj = tid >> 7, eb = tid & 127;
  float bir = 0.f, biz = 0.f, bin = 0.f, bhr = 0.f, bhz = 0.f, bhn = 0.f;
  if (tid < 512) {
    int j = j0 + ejj;
    bir = bih[j]; biz = bih[H_ + j]; bin = bih[2 * H_ + j];
    bhr = bhh[j]; bhz = bhh[H_ + j]; bhn = bhh[2 * H_ + j];
  }
  __syncthreads();

  // staging mapping (per thread, constant)
  const int kq_loc = tid >> 7;           // 0..7
  const int sb     = tid & 127;          // staged batch
  const int s_nt   = sb >> 4;
  const int lane_w = (sb & 15) + ((kq_loc >> 1) << 4);
  const int sub8   = (kq_loc & 1) << 3;

  for (int t = 0; t < T_; ++t) {
    const float4* __restrict__ hp4 =
        (const float4*)ring + (size_t)(RING ? t : (t & 1)) * 32768;
    float* __restrict__ hnf =
        ring + (size_t)(RING ? (t + 1) : ((t + 1) & 1)) * 131072;
    const float4* __restrict__ xt_t = XT4 + (size_t)t * 16384;

    f32x4 acc = {0.f, 0.f, 0.f, 0.f};

    #pragma unroll 1
    for (int c = 0; c < 24; ++c) {
      // ---- stage 64-k chunk of B (x for c<8, h after) as bf16 hi/lo frags
      #pragma unroll
      for (int i = 0; i < 2; ++i) {
        int kqg = (c << 4) + kq_loc + (i << 3);
        float4 v;
        if (kqg < 128) {
          if (use_xt) v = xt_t[kqg * 128 + sb];
          else        v = *(const float4*)(X + ((size_t)sb * T_ + t) * IN_ + (kqg << 2));
        } else {
          v = RING ? hp4[(kqg - 128) * 128 + sb]
                   : ld_h4_sc1(hp4 + (kqg - 128) * 128 + sb);
        }
        uint32 h01, h23, l01, l23;
        split2(v.x, v.y, h01, l01);
        split2(v.z, v.w, h23, l23);
        int bo = boff(i, s_nt, lane_w) + sub8;
        *(uint2*)(lds + BB_HI + bo) = make_uint2(h01, h23);
        *(uint2*)(lds + BB_LO + bo) = make_uint2(l01, l23);
      }
      __syncthreads();
      // ---- MFMA: this wave's k-tile x n-tile, 3 split passes
      {
        int KT = (c << 1) + ktw;
        bf16x8 ah = *(const bf16x8*)(lds + A_HI + (KT << 10) + (lane << 4));
        bf16x8 al = *(const bf16x8*)(lds + A_LO + (KT << 10) + (lane << 4));
        int bo = boff(ktw, nt, lane);
        bf16x8 bh = *(const bf16x8*)(lds + BB_HI + bo);
        bf16x8 bl = *(const bf16x8*)(lds + BB_LO + bo);
        acc = __builtin_amdgcn_mfma_f32_16x16x32_bf16(ah, bh, acc, 0, 0, 0);
        acc = __builtin_amdgcn_mfma_f32_16x16x32_bf16(ah, bl, acc, 0, 0, 0);
        acc = __builtin_amdgcn_mfma_f32_16x16x32_bf16(al, bh, acc, 0, 0, 0);
      }
      __syncthreads();
    }

    // ---- k-slot reduce + gate epilogue (C layout: col=lane&15, row=(lane>>4)*4+reg)
    *(f32x4*)(lds + BB_HI + boff(ktw, nt, lane)) = acc;
    __syncthreads();
    if (tid < 512) {
      float sv[4];
      #pragma unroll
      for (int g = 0; g < 4; ++g) {
        int r  = (g << 2) + ejj;
        int lr = (eb & 15) + ((r >> 2) << 4);
        int rg = (r & 3) << 2;
        float v0 = *(const float*)(lds + BB_HI + boff(0, eb >> 4, lr) + rg);
        float v1 = *(const float*)(lds + BB_HI + boff(1, eb >> 4, lr) + rg);
        sv[g] = v0 + v1;
      }
      float rr = sigf(sv[0] + bir + bhr);
      float zz = sigf(sv[1] + biz + bhz);
      float nn = tanhf(sv[2] + bin + rr * (sv[3] + bhn));
      int hidx = ((blockIdx.x * 128 + eb) << 2) + ejj;
      float hpv;
      if (RING) hpv = ((const float*)hp4)[hidx];
      else      hpv = __hip_atomic_load(&((const float*)hp4)[hidx],
                                        __ATOMIC_RELAXED, __HIP_MEMORY_SCOPE_AGENT);
      float hv = (1.f - zz) * nn + zz * hpv;
      __hip_atomic_store(&hnf[hidx], hv, __ATOMIC_RELAXED, __HIP_MEMORY_SCOPE_AGENT);
    }
    gridbar(barr + t);   // entry syncthreads also protects LDS reuse next step
  }
}

// Final h4T -> hfin[b][k]
__global__ __launch_bounds__(256) void hfin_kernel(
    const float* __restrict__ h4, float* __restrict__ out)
{
  int idx = blockIdx.x * 256 + threadIdx.x;   // over 128*1024
  int b = idx >> 10, k = idx & 1023;
  out[idx] = h4[(((k >> 2) * 128 + b) << 2) + (k & 3)];
}

// Gating GRUs: one wave per batch, gate-per-lane, all state in regs.
__global__ __launch_bounds__(64, 1) void gating_kernel(
    const float* __restrict__ X,
    const float* __restrict__ gwih0, const float* __restrict__ gwhh0,
    const float* __restrict__ gbih0, const float* __restrict__ gbhh0,
    const float* __restrict__ gwih1, const float* __restrict__ gwhh1,
    const float* __restrict__ gbih1, const float* __restrict__ gbhh1,
    float* __restrict__ omega)
{
  const int b = blockIdx.x;
  const int g = threadIdx.x;
  const int u = g & 7;
  float wi0[GIN_] = {}, wh0[GH_] = {}, wi1[GH_] = {}, wh1[GH_] = {};
  float bi0 = 0.f, bh0 = 0.f, bi1 = 0.f, bh1 = 0.f;
  if (g < 3 * GH_) {
    #pragma unroll
    for (int i = 0; i < GIN_; ++i) wi0[i] = gwih0[g * GIN_ + i];
    #pragma unroll
    for (int k = 0; k < GH_; ++k) { wh0[k] = gwhh0[g * GH_ + k]; wi1[k] = gwih1[g * GH_ + k]; wh1[k] = gwhh1[g * GH_ + k]; }
    bi0 = gbih0[g]; bh0 = gbhh0[g]; bi1 = gbih1[g]; bh1 = gbhh1[g];
  }
  float h0[GH_] = {}, h1[GH_] = {};
  for (int t = 0; t < T_; ++t) {
    float xt[GIN_];
    #pragma unroll
    for (int i = 0; i < GIN_; ++i) xt[i] = X[((size_t)b * T_ + t) * IN_ + (IN_ - GIN_) + i];
    float px = bi0, ph = bh0;
    #pragma unroll
    for (int i = 0; i < GIN_; ++i) px = fmaf(xt[i], wi0[i], px);
    #pragma unroll
    for (int k = 0; k < GH_; ++k) ph = fmaf(h0[k], wh0[k], ph);
    float s = px + ph;
    float s_r = __shfl(s, u);
    float s_z = __shfl(s, 8 + u);
    float nval = tanhf(px + sigf(s_r) * ph);
    float zval = sigf(s_z);
    float hnew = (1.f - zval) * nval + zval * h0[u];
    #pragma unroll
    for (int k = 0; k < GH_; ++k) h0[k] = __shfl(hnew, 16 + k);
    float px1 = bi1, ph1 = bh1;
    #pragma unroll
    for (int k = 0; k < GH_; ++k) px1 = fmaf(h0[k], wi1[k], px1);
    #pragma unroll
    for (int k = 0; k < GH_; ++k) ph1 = fmaf(h1[k], wh1[k], ph1);
    float s1 = px1 + ph1;
    float s1r = __shfl(s1, u);
    float s1z = __shfl(s1, 8 + u);
    float n1 = tanhf(px1 + sigf(s1r) * ph1);
    float z1 = sigf(s1z);
    float h1new = (1.f - z1) * n1 + z1 * h1[u];
    #pragma unroll
    for (int k = 0; k < GH_; ++k) h1[k] = __shfl(h1new, 16 + k);
  }
  if (g < GH_) {
    float m = h1[0];
    #pragma unroll
    for (int k = 1; k < GH_; ++k) m = fmaxf(m, h1[k]);
    float sum = 0.f;
    #pragma unroll
    for (int k = 0; k < GH_; ++k) sum += expf(h1[k] - m);
    omega[b * GH_ + g] = expf(h1[g] - m) / sum;
  }
}

// MoE layer: out[b,j] = act( sum_e omega[b,e] * (dot(in[b,:],w[e,:,j]) + bias[e,j]) )
__global__ __launch_bounds__(256, 2) void moe_kernel(
    const float* __restrict__ in, const float* __restrict__ w,
    const float* __restrict__ bias, const float* __restrict__ omega,
    float* __restrict__ out, int K, int act)
{
  __shared__ float4 lin4[64 * 32];
  __shared__ float  ldsw[E_ * 4 * 128];
  const int tid  = threadIdx.x;
  const int bh   = blockIdx.x & 1;
  const int jt   = blockIdx.x >> 1;
  const int wv   = tid >> 6;
  const int lane = tid & 63;
  const int j0   = jt * 4;
  const int j    = __builtin_amdgcn_readfirstlane(j0 + wv);
  const int b    = bh * 64 + lane;

  float acc[E_] = {0.f,0.f,0.f,0.f,0.f,0.f,0.f,0.f};
  const float4* row4 = &lin4[lane * 32];
  const int nch = K / 128;

  for (int c = 0; c < nch; ++c) {
    __syncthreads();
    const int k0 = c * 128;
    #pragma unroll
    for (int it = 0; it < 8; ++it) {
      int f = it * 256 + tid;
      int bb = f >> 5, q = f & 31;
      float4 v = *(const float4*)(in + (size_t)(bh * 64 + bb) * K + k0 + q * 4);
      lin4[bb * 32 + ((q & 24) | ((q ^ bb) & 7))] = v;
    }
    #pragma unroll
    for (int it = 0; it < 4; ++it) {
      int f = it * 256 + tid;
      int e = f >> 7, k = f & 127;
      float4 v = *(const float4*)(w + ((size_t)e * K + k0 + k) * HH_ + j0);
      ldsw[(e * 4 + 0) * 128 + k] = v.x;
      ldsw[(e * 4 + 1) * 128 + k] = v.y;
      ldsw[(e * 4 + 2) * 128 + k] = v.z;
      ldsw[(e * 4 + 3) * 128 + k] = v.w;
    }
    __syncthreads();
    #pragma unroll 2
    for (int q = 0; q < 32; ++q) {
      float4 xv = row4[(q & 24) | ((q ^ lane) & 7)];
      #pragma unroll
      for (int e = 0; e < E_; ++e) {
        const float4 wq = *(const float4*)&ldsw[(e * 4 + wv) * 128 + 4 * q];
        acc[e] = fmaf(xv.x, wq.x, acc[e]);
        acc[e] = fmaf(xv.y, wq.y, acc[e]);
        acc[e] = fmaf(xv.z, wq.z, acc[e]);
        acc[e] = fmaf(xv.w, wq.w, acc[e]);
      }
    }
  }

  float om[E_];
  #pragma unroll
  for (int e = 0; e < E_; ++e) om[e] = omega[b * E_ + e];
  float v = 0.f;
  #pragma unroll
  for (int e = 0; e < E_; ++e) v = fmaf(om[e], acc[e] + bias[e * HH_ + j], v);
  if (act == 0) v = (v > 0.f) ? v : expm1f(v);
  else          v = fminf(fmaxf(v, 0.f), 1.f);
  out[(size_t)b * HH_ + j] = v;
}

extern "C" void kernel_launch(void* const* d_in, const int* in_sizes, int n_in,
                              void* d_out, int out_size, void* d_ws, size_t ws_size,
                              hipStream_t stream) {
  (void)in_sizes; (void)n_in; (void)out_size;
  const float* X     = (const float*)d_in[0];
  const float* gwih0 = (const float*)d_in[1];
  const float* gwhh0 = (const float*)d_in[2];
  const float* gbih0 = (const float*)d_in[3];
  const float* gbhh0 = (const float*)d_in[4];
  const float* gwih1 = (const float*)d_in[5];
  const float* gwhh1 = (const float*)d_in[6];
  const float* gbih1 = (const float*)d_in[7];
  const float* gbhh1 = (const float*)d_in[8];
  const float* mwih  = (const float*)d_in[9];
  const float* mwhh  = (const float*)d_in[10];
  const float* mbih  = (const float*)d_in[11];
  const float* mbhh  = (const float*)d_in[12];
  const float* w1    = (const float*)d_in[13];
  const float* b1    = (const float*)d_in[14];
  const float* w2    = (const float*)d_in[15];
  const float* b2    = (const float*)d_in[16];
  const float* w3    = (const float*)d_in[17];
  const float* b3    = (const float*)d_in[18];

  const size_t HBUF = (size_t)B_ * H_;                  // 131072 floats
  const size_t XTF  = (size_t)T_ * IN_ * B_;            // 6.55M floats
  size_t ringA = 256 + (size_t)(T_ + 1) * HBUF + HBUF + 1024 + 2 * (size_t)B_ * HH_ + XTF;
  size_t ringB = 256 + 2 * HBUF + HBUF + 1024 + 2 * (size_t)B_ * HH_ + XTF;
  int tierA   = ws_size >= ringA * sizeof(float);
  int use_xt  = tierA || (ws_size >= ringB * sizeof(float));
  int R       = tierA ? (T_ + 1) : 2;

  float* ws = (float*)d_ws;
  unsigned* barr = (unsigned*)ws;
  float* ring = ws + 256;
  float* hfin = ring + (size_t)R * HBUF;
  float* om   = hfin + HBUF;
  float* a1   = om + 1024;
  float* a2   = a1 + (size_t)B_ * HH_;
  float* XT   = a2 + (size_t)B_ * HH_;

  // zero: barrier slots + ring[0] (initial hidden state)
  (void)hipMemsetAsync(d_ws, 0, (256 + HBUF) * sizeof(float), stream);
  (void)hipFuncSetAttribute((const void*)gru_mfma<true>,
                      hipFuncAttributeMaxDynamicSharedMemorySize, LDSZ);
  (void)hipFuncSetAttribute((const void*)gru_mfma<false>,
                      hipFuncAttributeMaxDynamicSharedMemorySize, LDSZ);

  gating_kernel<<<128, 64, 0, stream>>>(X, gwih0, gwhh0, gbih0, gbhh0,
                                        gwih1, gwhh1, gbih1, gbhh1, om);
  if (use_xt)
    xt_kernel<<<(T_ * 128 * 128) / 256, 256, 0, stream>>>(X, (float4*)XT);

  if (tierA)
    gru_mfma<true><<<256, 1024, LDSZ, stream>>>((const float4*)XT, X, use_xt,
        mwih, mwhh, mbih, mbhh, ring, barr);
  else
    gru_mfma<false><<<256, 1024, LDSZ, stream>>>((const float4*)XT, X, use_xt,
        mwih, mwhh, mbih, mbhh, ring, barr);

  const float* hlast = ring + (size_t)(tierA ? T_ : (T_ & 1)) * HBUF;
  hfin_kernel<<<512, 256, 0, stream>>>(hlast, hfin);
  moe_kernel<<<256, 256, 0, stream>>>(hfin, w1, b1, om, a1, H_, 0);
  moe_kernel<<<256, 256, 0, stream>>>(a1, w2, b2, om, a2, HH_, 0);
  moe_kernel<<<256, 256, 0, stream>>>(a2, w3, b3, om, (float*)d_out, HH_, 1);
}

// Round 11
// 1758.257 us; speedup vs baseline: 2.0598x; 2.0598x over previous
//
#include <hip/hip_runtime.h>
#include <cmath>

#define B_   128
#define T_   100
#define IN_  512
#define H_   1024
#define E_   8
#define HH_  512
#define GIN_ 5
#define GH_  8

// ---- tierS (plane) LDS layout: A hi 0..48K, A lo 48K..96K, B 3x16KB bufs
#define A_LO_  49152
#define BOFF_  98304
#define LDSZ2  147456
// ---- r10 fallback LDS layout
#define A_LOF 49152
#define BB_HI 98304
#define BB_LO 114688
#define LDSZF 131072

typedef unsigned long long u64t;
typedef unsigned int uint32;
typedef __attribute__((ext_vector_type(8))) short bf16x8;
typedef __attribute__((ext_vector_type(4))) float f32x4;

__device__ __forceinline__ float sigf(float x) { return 1.0f / (1.0f + expf(-x)); }

__device__ __forceinline__ float4 ld_h4_sc1(const float4* p) {
  const u64t* q = (const u64t*)p;
  u64t a = __hip_atomic_load(q,     __ATOMIC_RELAXED, __HIP_MEMORY_SCOPE_AGENT);
  u64t b = __hip_atomic_load(q + 1, __ATOMIC_RELAXED, __HIP_MEMORY_SCOPE_AGENT);
  union { u64t u; float2 f; } ca, cb;
  ca.u = a; cb.u = b;
  return make_float4(ca.f.x, ca.f.y, cb.f.x, cb.f.y);
}

__device__ __forceinline__ void st_u64_sc1(void* p, u64t v) {
  __hip_atomic_store((u64t*)p, v, __ATOMIC_RELAXED, __HIP_MEMORY_SCOPE_AGENT);
}

// Grid barrier without cache invalidation (sc1 stores + fresh ring buffers).
__device__ __forceinline__ void gridbar(unsigned* c) {
  __syncthreads();
  if (threadIdx.x == 0) {
    __hip_atomic_fetch_add(c, 1u, __ATOMIC_RELEASE, __HIP_MEMORY_SCOPE_AGENT);
    while (__hip_atomic_load(c, __ATOMIC_RELAXED, __HIP_MEMORY_SCOPE_AGENT) < gridDim.x) {
      __builtin_amdgcn_s_sleep(1);
    }
  }
  __syncthreads();
}

__device__ __forceinline__ uint32 bf16_rne(float f) {
  uint32 u = __builtin_bit_cast(uint32, f);
  return (u + 0x7FFFu + ((u >> 16) & 1u)) >> 16;
}

__device__ __forceinline__ void split2(float f0, float f1, uint32& h, uint32& l) {
  uint32 h0 = bf16_rne(f0), h1 = bf16_rne(f1);
  float hf0 = __builtin_bit_cast(float, h0 << 16);
  float hf1 = __builtin_bit_cast(float, h1 << 16);
  uint32 l0 = bf16_rne(f0 - hf0), l1 = bf16_rne(f1 - hf1);
  h = h0 | (h1 << 16);
  l = l0 | (l1 << 16);
}

// async 16B/lane global -> LDS (LDS dest wave-uniform; HW appends lane*16)
__device__ __forceinline__ void gl_lds16(const char* g, char* l) {
  __builtin_amdgcn_global_load_lds(
      (const __attribute__((address_space(1))) uint32*)(const void*)g,
      (__attribute__((address_space(3))) uint32*)(void*)l, 16, 0, 0);
}

// ---- one-shot: X -> bf16 hi/lo planes in MFMA-B fragment layout
// layout [p][t][KT 0..15][nt 0..7][lane*16B]
__global__ __launch_bounds__(256) void xsplit_kernel(
    const float* __restrict__ X, char* __restrict__ xpl)
{
  int idx = blockIdx.x * 256 + threadIdx.x;     // < 819200
  int lane = idx & 63;
  int n   = (idx >> 6) & 7;
  int KT  = (idx >> 9) & 15;
  int t   = idx >> 13;
  int b   = n * 16 + (lane & 15);
  int k   = KT * 32 + ((lane >> 4) << 3);
  const float* src = X + ((size_t)b * T_ + t) * IN_ + k;
  float4 va = *(const float4*)src;
  float4 vb = *(const float4*)(src + 4);
  uint32 h0,h1,h2,h3,l0,l1,l2,l3;
  split2(va.x, va.y, h0, l0); split2(va.z, va.w, h1, l1);
  split2(vb.x, vb.y, h2, l2); split2(vb.z, vb.w, h3, l3);
  size_t off = ((((size_t)t * 16 + KT) * 8 + n) << 10) + ((size_t)lane << 4);
  *(uint4*)(xpl + off)            = make_uint4(h0, h1, h2, h3);
  *(uint4*)(xpl + 13107200 + off) = make_uint4(l0, l1, l2, l3);
}

// ================= tierS persistent GRU: planes + global_load_lds pipeline ====
// 256 blocks x 1024 threads (16 waves = 8 nt x 2 ktw), 1 block/CU, LDS 144KB.
// A (weights, bf16 hi/lo frags) resident in LDS. B staged per 32-k chunk via
// one global_load_lds per wave, 3-deep buffers, counted vmcnt, raw barriers.
__global__ __launch_bounds__(1024, 4) void gru_mfma2(
    const char* __restrict__ xpl, char* __restrict__ ringp,
    const float* __restrict__ wih, const float* __restrict__ whh,
    const float* __restrict__ bih, const float* __restrict__ bhh,
    float* __restrict__ hq, unsigned* __restrict__ barr)
{
  extern __shared__ char lds[];
  const int tid  = threadIdx.x;
  const int lane = tid & 63;
  const int wv   = __builtin_amdgcn_readfirstlane(tid >> 6);
  const int nt   = wv & 7;
  const int ktw  = wv >> 3;
  const int j0   = blockIdx.x << 2;

  // ---- one-time: weights -> A fragments (bf16 hi/lo) [r10-proven mapping]
  for (int ii = tid * 2; ii < 24576; ii += 2048) {
    int r = ii / 1536, k = ii - r * 1536;
    int jj = r & 3, g = r >> 2;
    float f0, f1;
    if (k < IN_) {
      if (g == 3) { f0 = 0.f; f1 = 0.f; }
      else {
        const float* p = wih + (size_t)(((g == 2 ? 2 : g) * H_) + j0 + jj) * IN_ + k;
        f0 = p[0]; f1 = p[1];
      }
    } else {
      if (g == 2) { f0 = 0.f; f1 = 0.f; }
      else {
        const float* p = whh + (size_t)(((g == 3 ? 2 : g) * H_) + j0 + jj) * H_ + (k - IN_);
        f0 = p[0]; f1 = p[1];
      }
    }
    uint32 h, l; split2(f0, f1, h, l);
    int KT = k >> 5, k32 = k & 31;
    int ln  = r + ((k32 >> 3) << 4);
    int off = (KT << 10) + (ln << 4) + ((k32 & 7) << 1);
    *(uint32*)(lds + off)         = h;
    *(uint32*)(lds + A_LO_ + off) = l;
  }

  // epilogue biases (threads 0..511: ejj x eb)
  const int ejj = tid >> 7, eb = tid & 127;
  float bir = 0.f, biz = 0.f, bin = 0.f, bhr = 0.f, bhz = 0.f, bhn = 0.f;
  if (tid < 512) {
    int j = j0 + ejj;
    bir = bih[j]; biz = bih[H_ + j]; bin = bih[2 * H_ + j];
    bhr = bhh[j]; bhz = bhh[H_ + j]; bhn = bhh[2 * H_ + j];
  }
  float hprev_r = 0.f;                           // register h_prev (fixed j,b)
  __syncthreads();

  // wave staging bases: this wave stages plane p=ktw, n-tile nt of every chunk
  const char* xsrc0 = xpl + (size_t)ktw * 13107200 + ((size_t)nt << 10) + ((size_t)lane << 4);
  const char* hsrc0 = ringp + (size_t)ktw * 262144 + ((size_t)nt << 10) + ((size_t)lane << 4);
  char* const tilebase = lds + BOFF_ + (((ktw << 3) + nt) << 10);  // uniform

  // epilogue plane-write constants (tid<128 path)
  const size_t pw_off = ((((size_t)(j0 >> 5)) * 8) << 10);

  for (int t = 0; t < T_; ++t) {
    const char* xs = xsrc0 + (size_t)t * 131072;
    const char* hs = hsrc0 + (size_t)t * 524288;
    f32x4 acc = {0.f, 0.f, 0.f, 0.f};

#define STAGE(cc) { const char* g = ((cc) < 16) ? (xs + (size_t)(cc) * 8192) \
                                                : (hs + (size_t)((cc) - 16) * 8192); \
                    gl_lds16(g, lds + BOFF_ + ((cc) % 3) * 16384 - BOFF_ + BOFF_ \
                             + (((ktw << 3) + nt) << 10) - (((ktw << 3) + nt) << 10) \
                             + ((cc) % 3) * 0); }
#undef STAGE
    // (explicit staging below; macro above intentionally unused)

    // prologue: chunks 0,1
    gl_lds16(xs + 0 * 8192, tilebase + 0 * 16384);
    gl_lds16(xs + 1 * 8192, tilebase + 1 * 16384);

    #pragma unroll
    for (int c = 0; c < 48; ++c) {
      if (c < 46) {
        const int cn = c + 2;
        const char* g = (cn < 16) ? (xs + (size_t)cn * 8192)
                                  : (hs + (size_t)(cn - 16) * 8192);
        gl_lds16(g, tilebase + (cn % 3) * 16384);
        asm volatile("s_waitcnt vmcnt(2)" ::: "memory");
      } else if (c == 46) {
        asm volatile("s_waitcnt vmcnt(1)" ::: "memory");
      } else {
        asm volatile("s_waitcnt vmcnt(0)" ::: "memory");
      }
      __builtin_amdgcn_s_barrier();
      __builtin_amdgcn_sched_barrier(0);
      if (ktw == (c & 1)) {
        bf16x8 ah = *(const bf16x8*)(lds + (c << 10) + (lane << 4));
        bf16x8 al = *(const bf16x8*)(lds + A_LO_ + (c << 10) + (lane << 4));
        const char* bb = lds + BOFF_ + (c % 3) * 16384;
        bf16x8 bh = *(const bf16x8*)(bb + (nt << 10) + (lane << 4));
        bf16x8 bl = *(const bf16x8*)(bb + 8192 + (nt << 10) + (lane << 4));
        acc = __builtin_amdgcn_mfma_f32_16x16x32_bf16(ah, bh, acc, 0, 0, 0);
        acc = __builtin_amdgcn_mfma_f32_16x16x32_bf16(ah, bl, acc, 0, 0, 0);
        acc = __builtin_amdgcn_mfma_f32_16x16x32_bf16(al, bh, acc, 0, 0, 0);
      }
      __builtin_amdgcn_sched_barrier(0);
      __builtin_amdgcn_s_barrier();
    }

    // ---- kslot reduce via dump in buf0; epilogue
    *(f32x4*)(lds + BOFF_ + (((ktw << 3) + nt) << 10) + (lane << 4)) = acc;
    __syncthreads();

    if (tid < 512) {
      float sv[4];
      #pragma unroll
      for (int g = 0; g < 4; ++g) {
        int lr = (eb & 15) | (g << 4);
        const char* d0 = lds + BOFF_ + (((eb >> 4)) << 10) + (lr << 4) + (ejj << 2);
        float v0 = *(const float*)d0;
        float v1 = *(const float*)(d0 + 8192);
        sv[g] = v0 + v1;
      }
      float rr = sigf(sv[0] + bir + bhr);
      float zz = sigf(sv[1] + biz + bhz);
      float nn = tanhf(sv[2] + bin + rr * (sv[3] + bhn));
      float hv = (1.f - zz) * nn + zz * hprev_r;
      hprev_r = hv;
      ((float*)(lds + BOFF_ + 16384))[(ejj << 7) + eb] = hv;
      if (t == T_ - 1) hq[((blockIdx.x * 128 + eb) << 2) + ejj] = hv;
    }
    __syncthreads();

    if (tid < 128) {
      const int b = tid;
      const float* hl = (const float*)(lds + BOFF_ + 16384);
      uint32 hh[4], ll[4];
      #pragma unroll
      for (int i = 0; i < 4; ++i) {
        float v = hl[(i << 7) + b];
        uint32 hb = bf16_rne(v);
        float hf = __builtin_bit_cast(float, hb << 16);
        ll[i] = bf16_rne(v - hf);
        hh[i] = hb;
      }
      u64t HI = (u64t)hh[0] | ((u64t)hh[1] << 16) | ((u64t)hh[2] << 32) | ((u64t)hh[3] << 48);
      u64t LO = (u64t)ll[0] | ((u64t)ll[1] << 16) | ((u64t)ll[2] << 32) | ((u64t)ll[3] << 48);
      int lane_w = (((j0 & 31) >> 3) << 4) | (b & 15);
      size_t byteoff = pw_off + (((size_t)(b >> 4)) << 10) + ((size_t)lane_w << 4) + ((j0 & 4) ? 8 : 0);
      char* base = ringp + (size_t)(t + 1) * 524288;
      st_u64_sc1(base + byteoff, HI);
      st_u64_sc1(base + 262144 + byteoff, LO);
    }
    gridbar(barr + t);
  }
}

// ================= r10 fallback kernel (proven) ==============================
__device__ __forceinline__ int boff(int kt, int nt, int lane) {
  return (((((kt << 3) + nt) << 6) + lane) << 4) ^ ((nt & 3) << 5);
}

__global__ __launch_bounds__(256) void xt_kernel(
    const float* __restrict__ X, float4* __restrict__ XT4)
{
  int idx = blockIdx.x * 256 + threadIdx.x;
  int b  = idx & 127;
  int kq = (idx >> 7) & 127;
  int t  = idx >> 14;
  XT4[idx] = *(const float4*)(X + ((size_t)b * T_ + t) * IN_ + kq * 4);
}

template<bool RING>
__global__ __launch_bounds__(1024, 4) void gru_mfma(
    const float4* __restrict__ XT4, const float* __restrict__ X, int use_xt,
    const float* __restrict__ wih, const float* __restrict__ whh,
    const float* __restrict__ bih, const float* __restrict__ bhh,
    float* __restrict__ ring, unsigned* __restrict__ barr)
{
  extern __shared__ char lds[];
  const int tid  = threadIdx.x;
  const int lane = tid & 63;
  const int wv   = __builtin_amdgcn_readfirstlane(tid >> 6);
  const int nt   = wv & 7;
  const int ktw  = wv >> 3;
  const int j0   = blockIdx.x << 2;

  for (int ii = tid * 2; ii < 24576; ii += 2048) {
    int r = ii / 1536, k = ii - r * 1536;
    int jj = r & 3, g = r >> 2;
    float f0, f1;
    if (k < IN_) {
      if (g == 3) { f0 = 0.f; f1 = 0.f; }
      else {
        const float* p = wih + (size_t)(((g == 2 ? 2 : g) * H_) + j0 + jj) * IN_ + k;
        f0 = p[0]; f1 = p[1];
      }
    } else {
      if (g == 2) { f0 = 0.f; f1 = 0.f; }
      else {
        const float* p = whh + (size_t)(((g == 3 ? 2 : g) * H_) + j0 + jj) * H_ + (k - IN_);
        f0 = p[0]; f1 = p[1];
      }
    }
    uint32 h, l; split2(f0, f1, h, l);
    int KT = k >> 5, k32 = k & 31;
    int ln  = r + ((k32 >> 3) << 4);
    int off = (KT << 10) + (ln << 4) + ((k32 & 7) << 1);
    *(uint32*)(lds + off)         = h;
    *(uint32*)(lds + A_LOF + off) = l;
  }

  const int ejj = tid >> 7, eb = tid & 127;
  float bir = 0.f, biz = 0.f, bin = 0.f, bhr = 0.f, bhz = 0.f, bhn = 0.f;
  if (tid < 512) {
    int j = j0 + ejj;
    bir = bih[j]; biz = bih[H_ + j]; bin = bih[2 * H_ + j];
    bhr = bhh[j]; bhz = bhh[H_ + j]; bhn = bhh[2 * H_ + j];
  }
  __syncthreads();

  const int kq_loc = tid >> 7;
  const int sb     = tid & 127;
  const int s_nt   = sb >> 4;
  const int lane_w = (sb & 15) + ((kq_loc >> 1) << 4);
  const int sub8   = (kq_loc & 1) << 3;

  for (int t = 0; t < T_; ++t) {
    const float4* __restrict__ hp4 =
        (const float4*)ring + (size_t)(RING ? t : (t & 1)) * 32768;
    float* __restrict__ hnf =
        ring + (size_t)(RING ? (t + 1) : ((t + 1) & 1)) * 131072;
    const float4* __restrict__ xt_t = XT4 + (size_t)t * 16384;

    f32x4 acc = {0.f, 0.f, 0.f, 0.f};

    #pragma unroll 1
    for (int c = 0; c < 24; ++c) {
      #pragma unroll
      for (int i = 0; i < 2; ++i) {
        int kqg = (c << 4) + kq_loc + (i << 3);
        float4 v;
        if (kqg < 128) {
          if (use_xt) v = xt_t[kqg * 128 + sb];
          else        v = *(const float4*)(X + ((size_t)sb * T_ + t) * IN_ + (kqg << 2));
        } else {
          v = RING ? hp4[(kqg - 128) * 128 + sb]
                   : ld_h4_sc1(hp4 + (kqg - 128) * 128 + sb);
        }
        uint32 h01, h23, l01, l23;
        split2(v.x, v.y, h01, l01);
        split2(v.z, v.w, h23, l23);
        int bo = boff(i, s_nt, lane_w) + sub8;
        *(uint2*)(lds + BB_HI + bo) = make_uint2(h01, h23);
        *(uint2*)(lds + BB_LO + bo) = make_uint2(l01, l23);
      }
      __syncthreads();
      {
        int KT = (c << 1) + ktw;
        bf16x8 ah = *(const bf16x8*)(lds + (KT << 10) + (lane << 4));
        bf16x8 al = *(const bf16x8*)(lds + A_LOF + (KT << 10) + (lane << 4));
        int bo = boff(ktw, nt, lane);
        bf16x8 bh = *(const bf16x8*)(lds + BB_HI + bo);
        bf16x8 bl = *(const bf16x8*)(lds + BB_LO + bo);
        acc = __builtin_amdgcn_mfma_f32_16x16x32_bf16(ah, bh, acc, 0, 0, 0);
        acc = __builtin_amdgcn_mfma_f32_16x16x32_bf16(ah, bl, acc, 0, 0, 0);
        acc = __builtin_amdgcn_mfma_f32_16x16x32_bf16(al, bh, acc, 0, 0, 0);
      }
      __syncthreads();
    }

    *(f32x4*)(lds + BB_HI + boff(ktw, nt, lane)) = acc;
    __syncthreads();
    if (tid < 512) {
      float sv[4];
      #pragma unroll
      for (int g = 0; g < 4; ++g) {
        int r  = (g << 2) + ejj;
        int lr = (eb & 15) + ((r >> 2) << 4);
        int rg = (r & 3) << 2;
        float v0 = *(const float*)(lds + BB_HI + boff(0, eb >> 4, lr) + rg);
        float v1 = *(const float*)(lds + BB_HI + boff(1, eb >> 4, lr) + rg);
        sv[g] = v0 + v1;
      }
      float rr = sigf(sv[0] + bir + bhr);
      float zz = sigf(sv[1] + biz + bhz);
      float nn = tanhf(sv[2] + bin + rr * (sv[3] + bhn));
      int hidx = ((blockIdx.x * 128 + eb) << 2) + ejj;
      float hpv;
      if (RING) hpv = ((const float*)hp4)[hidx];
      else      hpv = __hip_atomic_load(&((const float*)hp4)[hidx],
                                        __ATOMIC_RELAXED, __HIP_MEMORY_SCOPE_AGENT);
      float hv = (1.f - zz) * nn + zz * hpv;
      __hip_atomic_store(&hnf[hidx], hv, __ATOMIC_RELAXED, __HIP_MEMORY_SCOPE_AGENT);
    }
    gridbar(barr + t);
  }
}

// Final h4T -> hfin[b][k]
__global__ __launch_bounds__(256) void hfin_kernel(
    const float* __restrict__ h4, float* __restrict__ out)
{
  int idx = blockIdx.x * 256 + threadIdx.x;
  int b = idx >> 10, k = idx & 1023;
  out[idx] = h4[(((k >> 2) * 128 + b) << 2) + (k & 3)];
}

// Gating GRUs: one wave per batch, gate-per-lane, all state in regs.
__global__ __launch_bounds__(64, 1) void gating_kernel(
    const float* __restrict__ X,
    const float* __restrict__ gwih0, const float* __restrict__ gwhh0,
    const float* __restrict__ gbih0, const float* __restrict__ gbhh0,
    const float* __restrict__ gwih1, const float* __restrict__ gwhh1,
    const float* __restrict__ gbih1, const float* __restrict__ gbhh1,
    float* __restrict__ omega)
{
  const int b = blockIdx.x;
  const int g = threadIdx.x;
  const int u = g & 7;
  float wi0[GIN_] = {}, wh0[GH_] = {}, wi1[GH_] = {}, wh1[GH_] = {};
  float bi0 = 0.f, bh0 = 0.f, bi1 = 0.f, bh1 = 0.f;
  if (g < 3 * GH_) {
    #pragma unroll
    for (int i = 0; i < GIN_; ++i) wi0[i] = gwih0[g * GIN_ + i];
    #pragma unroll
    for (int k = 0; k < GH_; ++k) { wh0[k] = gwhh0[g * GH_ + k]; wi1[k] = gwih1[g * GH_ + k]; wh1[k] = gwhh1[g * GH_ + k]; }
    bi0 = gbih0[g]; bh0 = gbhh0[g]; bi1 = gbih1[g]; bh1 = gbhh1[g];
  }
  float h0[GH_] = {}, h1[GH_] = {};
  for (int t = 0; t < T_; ++t) {
    float xt[GIN_];
    #pragma unroll
    for (int i = 0; i < GIN_; ++i) xt[i] = X[((size_t)b * T_ + t) * IN_ + (IN_ - GIN_) + i];
    float px = bi0, ph = bh0;
    #pragma unroll
    for (int i = 0; i < GIN_; ++i) px = fmaf(xt[i], wi0[i], px);
    #pragma unroll
    for (int k = 0; k < GH_; ++k) ph = fmaf(h0[k], wh0[k], ph);
    float s = px + ph;
    float s_r = __shfl(s, u);
    float s_z = __shfl(s, 8 + u);
    float nval = tanhf(px + sigf(s_r) * ph);
    float zval = sigf(s_z);
    float hnew = (1.f - zval) * nval + zval * h0[u];
    #pragma unroll
    for (int k = 0; k < GH_; ++k) h0[k] = __shfl(hnew, 16 + k);
    float px1 = bi1, ph1 = bh1;
    #pragma unroll
    for (int k = 0; k < GH_; ++k) px1 = fmaf(h0[k], wi1[k], px1);
    #pragma unroll
    for (int k = 0; k < GH_; ++k) ph1 = fmaf(h1[k], wh1[k], ph1);
    float s1 = px1 + ph1;
    float s1r = __shfl(s1, u);
    float s1z = __shfl(s1, 8 + u);
    float n1 = tanhf(px1 + sigf(s1r) * ph1);
    float z1 = sigf(s1z);
    float h1new = (1.f - z1) * n1 + z1 * h1[u];
    #pragma unroll
    for (int k = 0; k < GH_; ++k) h1[k] = __shfl(h1new, 16 + k);
  }
  if (g < GH_) {
    float m = h1[0];
    #pragma unroll
    for (int k = 1; k < GH_; ++k) m = fmaxf(m, h1[k]);
    float sum = 0.f;
    #pragma unroll
    for (int k = 0; k < GH_; ++k) sum += expf(h1[k] - m);
    omega[b * GH_ + g] = expf(h1[g] - m) / sum;
  }
}

// MoE layer
__global__ __launch_bounds__(256, 2) void moe_kernel(
    const float* __restrict__ in, const float* __restrict__ w,
    const float* __restrict__ bias, const float* __restrict__ omega,
    float* __restrict__ out, int K, int act)
{
  __shared__ float4 lin4[64 * 32];
  __shared__ float  ldsw[E_ * 4 * 128];
  const int tid  = threadIdx.x;
  const int bh   = blockIdx.x & 1;
  const int jt   = blockIdx.x >> 1;
  const int wv   = tid >> 6;
  const int lane = tid & 63;
  const int j0   = jt * 4;
  const int j    = __builtin_amdgcn_readfirstlane(j0 + wv);
  const int b    = bh * 64 + lane;

  float acc[E_] = {0.f,0.f,0.f,0.f,0.f,0.f,0.f,0.f};
  const float4* row4 = &lin4[lane * 32];
  const int nch = K / 128;

  for (int c = 0; c < nch; ++c) {
    __syncthreads();
    const int k0 = c * 128;
    #pragma unroll
    for (int it = 0; it < 8; ++it) {
      int f = it * 256 + tid;
      int bb = f >> 5, q = f & 31;
      float4 v = *(const float4*)(in + (size_t)(bh * 64 + bb) * K + k0 + q * 4);
      lin4[bb * 32 + ((q & 24) | ((q ^ bb) & 7))] = v;
    }
    #pragma unroll
    for (int it = 0; it < 4; ++it) {
      int f = it * 256 + tid;
      int e = f >> 7, k = f & 127;
      float4 v = *(const float4*)(w + ((size_t)e * K + k0 + k) * HH_ + j0);
      ldsw[(e * 4 + 0) * 128 + k] = v.x;
      ldsw[(e * 4 + 1) * 128 + k] = v.y;
      ldsw[(e * 4 + 2) * 128 + k] = v.z;
      ldsw[(e * 4 + 3) * 128 + k] = v.w;
    }
    __syncthreads();
    #pragma unroll 2
    for (int q = 0; q < 32; ++q) {
      float4 xv = row4[(q & 24) | ((q ^ lane) & 7)];
      #pragma unroll
      for (int e = 0; e < E_; ++e) {
        const float4 wq = *(const float4*)&ldsw[(e * 4 + wv) * 128 + 4 * q];
        acc[e] = fmaf(xv.x, wq.x, acc[e]);
        acc[e] = fmaf(xv.y, wq.y, acc[e]);
        acc[e] = fmaf(xv.z, wq.z, acc[e]);
        acc[e] = fmaf(xv.w, wq.w, acc[e]);
      }
    }
  }

  float om[E_];
  #pragma unroll
  for (int e = 0; e < E_; ++e) om[e] = omega[b * E_ + e];
  float v = 0.f;
  #pragma unroll
  for (int e = 0; e < E_; ++e) v = fmaf(om[e], acc[e] + bias[e * HH_ + j], v);
  if (act == 0) v = (v > 0.f) ? v : expm1f(v);
  else          v = fminf(fmaxf(v, 0.f), 1.f);
  out[(size_t)b * HH_ + j] = v;
}

extern "C" void kernel_launch(void* const* d_in, const int* in_sizes, int n_in,
                              void* d_out, int out_size, void* d_ws, size_t ws_size,
                              hipStream_t stream) {
  (void)in_sizes; (void)n_in; (void)out_size;
  const float* X     = (const float*)d_in[0];
  const float* gwih0 = (const float*)d_in[1];
  const float* gwhh0 = (const float*)d_in[2];
  const float* gbih0 = (const float*)d_in[3];
  const float* gbhh0 = (const float*)d_in[4];
  const float* gwih1 = (const float*)d_in[5];
  const float* gwhh1 = (const float*)d_in[6];
  const float* gbih1 = (const float*)d_in[7];
  const float* gbhh1 = (const float*)d_in[8];
  const float* mwih  = (const float*)d_in[9];
  const float* mwhh  = (const float*)d_in[10];
  const float* mbih  = (const float*)d_in[11];
  const float* mbhh  = (const float*)d_in[12];
  const float* w1    = (const float*)d_in[13];
  const float* b1    = (const float*)d_in[14];
  const float* w2    = (const float*)d_in[15];
  const float* b2    = (const float*)d_in[16];
  const float* w3    = (const float*)d_in[17];
  const float* b3    = (const float*)d_in[18];

  const size_t HBUF = (size_t)B_ * H_;                  // 131072 floats
  // tierS: barr + hq + planes(101x131072) + om + a1 + a2 + hfin + xplanes
  size_t tierS_f = 256 + HBUF + 101 * HBUF + 1024 + 2 * (size_t)B_ * HH_ + HBUF + 6553600;
  // r10 tiers
  const size_t XTF = (size_t)T_ * IN_ * B_;
  size_t ringA = 256 + (size_t)(T_ + 1) * HBUF + HBUF + 1024 + 2 * (size_t)B_ * HH_ + XTF;
  size_t ringB = 256 + 2 * HBUF + HBUF + 1024 + 2 * (size_t)B_ * HH_ + XTF;

  float* ws = (float*)d_ws;

  if (ws_size >= tierS_f * sizeof(float)) {
    unsigned* barr = (unsigned*)ws;
    float* hq    = ws + 256;
    float* ringp = hq + HBUF;                            // 101 x 131072 floats
    float* om    = ringp + 101 * HBUF;
    float* a1    = om + 1024;
    float* a2    = a1 + (size_t)B_ * HH_;
    float* hfin  = a2 + (size_t)B_ * HH_;
    float* xpl   = hfin + HBUF;

    (void)hipMemsetAsync(d_ws, 0, 256 * sizeof(float), stream);          // barr
    (void)hipMemsetAsync(ringp, 0, 524288, stream);                      // plane t=0
    (void)hipFuncSetAttribute((const void*)gru_mfma2,
                        hipFuncAttributeMaxDynamicSharedMemorySize, LDSZ2);

    gating_kernel<<<128, 64, 0, stream>>>(X, gwih0, gwhh0, gbih0, gbhh0,
                                          gwih1, gwhh1, gbih1, gbhh1, om);
    xsplit_kernel<<<3200, 256, 0, stream>>>(X, (char*)xpl);
    gru_mfma2<<<256, 1024, LDSZ2, stream>>>((const char*)xpl, (char*)ringp,
        mwih, mwhh, mbih, mbhh, hq, barr);
    hfin_kernel<<<512, 256, 0, stream>>>(hq, hfin);
    moe_kernel<<<256, 256, 0, stream>>>(hfin, w1, b1, om, a1, H_, 0);
    moe_kernel<<<256, 256, 0, stream>>>(a1, w2, b2, om, a2, HH_, 0);
    moe_kernel<<<256, 256, 0, stream>>>(a2, w3, b3, om, (float*)d_out, HH_, 1);
    return;
  }

  // -------- fallback: r10 proven path --------
  int tierA   = ws_size >= ringA * sizeof(float);
  int use_xt  = tierA || (ws_size >= ringB * sizeof(float));
  int R       = tierA ? (T_ + 1) : 2;

  unsigned* barr = (unsigned*)ws;
  float* ring = ws + 256;
  float* hfin = ring + (size_t)R * HBUF;
  float* om   = hfin + HBUF;
  float* a1   = om + 1024;
  float* a2   = a1 + (size_t)B_ * HH_;
  float* XT   = a2 + (size_t)B_ * HH_;

  (void)hipMemsetAsync(d_ws, 0, (256 + HBUF) * sizeof(float), stream);
  (void)hipFuncSetAttribute((const void*)gru_mfma<true>,
                      hipFuncAttributeMaxDynamicSharedMemorySize, LDSZF);
  (void)hipFuncSetAttribute((const void*)gru_mfma<false>,
                      hipFuncAttributeMaxDynamicSharedMemorySize, LDSZF);

  gating_kernel<<<128, 64, 0, stream>>>(X, gwih0, gwhh0, gbih0, gbhh0,
                                        gwih1, gwhh1, gbih1, gbhh1, om);
  if (use_xt)
    xt_kernel<<<(T_ * 128 * 128) / 256, 256, 0, stream>>>(X, (float4*)XT);

  if (tierA)
    gru_mfma<true><<<256, 1024, LDSZF, stream>>>((const float4*)XT, X, use_xt,
        mwih, mwhh, mbih, mbhh, ring, barr);
  else
    gru_mfma<false><<<256, 1024, LDSZF, stream>>>((const float4*)XT, X, use_xt,
        mwih, mwhh, mbih, mbhh, ring, barr);

  const float* hlast = ring + (size_t)(tierA ? T_ : (T_ & 1)) * HBUF;
  hfin_kernel<<<512, 256, 0, stream>>>(hlast, hfin);
  moe_kernel<<<256, 256, 0, stream>>>(hfin, w1, b1, om, a1, H_, 0);
  moe_kernel<<<256, 256, 0, stream>>>(a1, w2, b2, om, a2, HH_, 0);
  moe_kernel<<<256, 256, 0, stream>>>(a2, w3, b3, om, (float*)d_out, HH_, 1);
}

// Round 13
// 1757.877 us; speedup vs baseline: 2.0603x; 1.0002x over previous
//
#include <hip/hip_runtime.h>
#include <cmath>

#define B_   128
#define T_   100
#define IN_  512
#define H_   1024
#define E_   8
#define HH_  512
#define GIN_ 5
#define GH_  8

// ---- tierS LDS: A hi 0..40K (KT 0..39), A lo 40..80K, B 2 x 32KB buffers
#define A_LO_  40960
#define BOFF_  81920
#define BOFF2_ 114688          // dump region = buf1
#define LDSZ4  147456          // proven-launchable size (r11)
// ---- r10 fallback LDS layout
#define A_LOF 49152
#define BB_HI 98304
#define BB_LO 114688
#define LDSZF 131072

typedef unsigned long long u64t;
typedef unsigned int uint32;
typedef __attribute__((ext_vector_type(8))) short bf16x8;
typedef __attribute__((ext_vector_type(4))) float f32x4;

__device__ __forceinline__ float sigf(float x) { return 1.0f / (1.0f + expf(-x)); }

__device__ __forceinline__ float4 ld_h4_sc1(const float4* p) {
  const u64t* q = (const u64t*)p;
  u64t a = __hip_atomic_load(q,     __ATOMIC_RELAXED, __HIP_MEMORY_SCOPE_AGENT);
  u64t b = __hip_atomic_load(q + 1, __ATOMIC_RELAXED, __HIP_MEMORY_SCOPE_AGENT);
  union { u64t u; float2 f; } ca, cb;
  ca.u = a; cb.u = b;
  return make_float4(ca.f.x, ca.f.y, cb.f.x, cb.f.y);
}

__device__ __forceinline__ void st_u64_sc1(void* p, u64t v) {
  __hip_atomic_store((u64t*)p, v, __ATOMIC_RELAXED, __HIP_MEMORY_SCOPE_AGENT);
}

// Grid barrier without cache invalidation (sc1 stores + fresh ring buffers).
__device__ __forceinline__ void gridbar(unsigned* c) {
  __syncthreads();
  if (threadIdx.x == 0) {
    __hip_atomic_fetch_add(c, 1u, __ATOMIC_RELEASE, __HIP_MEMORY_SCOPE_AGENT);
    while (__hip_atomic_load(c, __ATOMIC_RELAXED, __HIP_MEMORY_SCOPE_AGENT) < gridDim.x) {
      __builtin_amdgcn_s_sleep(1);
    }
  }
  __syncthreads();
}

__device__ __forceinline__ uint32 bf16_rne(float f) {
  uint32 u = __builtin_bit_cast(uint32, f);
  return (u + 0x7FFFu + ((u >> 16) & 1u)) >> 16;
}

__device__ __forceinline__ void split2(float f0, float f1, uint32& h, uint32& l) {
  uint32 h0 = bf16_rne(f0), h1 = bf16_rne(f1);
  float hf0 = __builtin_bit_cast(float, h0 << 16);
  float hf1 = __builtin_bit_cast(float, h1 << 16);
  uint32 l0 = bf16_rne(f0 - hf0), l1 = bf16_rne(f1 - hf1);
  h = h0 | (h1 << 16);
  l = l0 | (l1 << 16);
}

// async 16B/lane global -> LDS (LDS dest wave-uniform; HW appends lane*16)
__device__ __forceinline__ void gl_lds16(const char* g, char* l) {
  __builtin_amdgcn_global_load_lds(
      (const __attribute__((address_space(1))) uint32*)(const void*)g,
      (__attribute__((address_space(3))) uint32*)(void*)l, 16, 0, 0);
}

// ---- one-shot: X -> bf16 hi/lo planes in MFMA-B fragment layout
// layout [p][t][KT 0..15][nt 0..7][lane*16B]
__global__ __launch_bounds__(256) void xsplit_kernel(
    const float* __restrict__ X, char* __restrict__ xpl)
{
  int idx = blockIdx.x * 256 + threadIdx.x;     // < 819200
  int lane = idx & 63;
  int n   = (idx >> 6) & 7;
  int KT  = (idx >> 9) & 15;
  int t   = idx >> 13;
  int b   = n * 16 + (lane & 15);
  int k   = KT * 32 + ((lane >> 4) << 3);
  const float* src = X + ((size_t)b * T_ + t) * IN_ + k;
  float4 va = *(const float4*)src;
  float4 vb = *(const float4*)(src + 4);
  uint32 h0,h1,h2,h3,l0,l1,l2,l3;
  split2(va.x, va.y, h0, l0); split2(va.z, va.w, h1, l1);
  split2(vb.x, vb.y, h2, l2); split2(vb.z, vb.w, h3, l3);
  size_t off = ((((size_t)t * 16 + KT) * 8 + n) << 10) + ((size_t)lane << 4);
  *(uint4*)(xpl + off)            = make_uint4(h0, h1, h2, h3);
  *(uint4*)(xpl + 13107200 + off) = make_uint4(l0, l1, l2, l3);
}

// stage one phase-pair slice: wave stages 2 x 1KB (nt = 2*snp, 2*snp+1)
__device__ __forceinline__ void stage_pair(
    char* lds, const char* xpl, const char* ringp,
    int q, int tx, int th, int sp, int spl, int snp, int lane)
{
  const int cc = 2 * q + sp;
  char* dst0 = lds + BOFF_ + ((q & 1) << 15) + (sp << 14) + (spl << 13);
  #pragma unroll
  for (int i = 0; i < 2; ++i) {
    const int nt = (snp << 1) + i;
    const char* src;
    if (cc < 16)
      src = xpl + (size_t)spl * 13107200
          + ((((size_t)tx * 16 + cc) * 8 + nt) << 10) + ((size_t)lane << 4);
    else
      src = ringp + (size_t)th * 524288 + ((size_t)spl << 18)
          + ((size_t)((cc - 16) * 8 + nt) << 10) + ((size_t)lane << 4);
    gl_lds16(src, dst0 + (nt << 10));
  }
}

// ============ tierS persistent GRU: 24 phases/step, all 16 waves active =======
// 256 blocks x 1024 threads, 1 block/CU, LDS 144KB (A 80K + 2x32K B bufs).
// A KT 0..39 in LDS; KT 40..47 in per-wave registers (parity-matched, 32 VGPR).
// Phase p: stage p+1 -> vmcnt(2) -> s_barrier -> 3 MFMA (chunk 2p+cw) -> s_barrier.
__global__ __launch_bounds__(1024, 4) void gru_mfma4(
    const char* __restrict__ xpl, char* __restrict__ ringp,
    const float* __restrict__ wih, const float* __restrict__ whh,
    const float* __restrict__ bih, const float* __restrict__ bhh,
    float* __restrict__ hq, unsigned* __restrict__ barr)
{
  extern __shared__ char lds[];
  const int tid  = threadIdx.x;
  const int lane = tid & 63;
  const int wv   = __builtin_amdgcn_readfirstlane(tid >> 6);
  // compute mapping
  const int cw   = wv >> 3;            // chunk parity
  const int ntc  = wv & 7;             // n-tile
  // stage mapping
  const int sp   = wv & 1;
  const int spl  = (wv >> 1) & 1;
  const int snp  = wv >> 2;            // 0..3 (wv>>2 & 3)
  const int j0   = blockIdx.x << 2;

  // ---- one-time: weights KT 0..39 -> A fragments (bf16 hi/lo) in LDS
  for (int ii = tid * 2; ii < 20480; ii += 2048) {
    int r = ii / 1280, k = ii - r * 1280;
    int jj = r & 3, g = r >> 2;
    float f0, f1;
    if (k < IN_) {
      if (g == 3) { f0 = 0.f; f1 = 0.f; }
      else {
        const float* p = wih + (size_t)(((g == 2 ? 2 : g) * H_) + j0 + jj) * IN_ + k;
        f0 = p[0]; f1 = p[1];
      }
    } else {
      if (g == 2) { f0 = 0.f; f1 = 0.f; }
      else {
        const float* p = whh + (size_t)(((g == 3 ? 2 : g) * H_) + j0 + jj) * H_ + (k - IN_);
        f0 = p[0]; f1 = p[1];
      }
    }
    uint32 h, l; split2(f0, f1, h, l);
    int KT = k >> 5, k32 = k & 31;
    int ln  = r + ((k32 >> 3) << 4);
    int off = (KT << 10) + (ln << 4) + ((k32 & 7) << 1);
    *(uint32*)(lds + off)         = h;
    *(uint32*)(lds + A_LO_ + off) = l;
  }

  // ---- one-time: A-frags for KT 40+2i+cw (i=0..3) into registers
  bf16x8 rah[4], ral[4];
  {
    const int rr = lane & 15, k8 = lane >> 4;
    const int jj = rr & 3, g = rr >> 2;
    #pragma unroll
    for (int i = 0; i < 4; ++i) {
      const int KT = 40 + 2 * i + cw;
      const int kh = KT * 32 + k8 * 8 - IN_;   // 768..1023 (h-range always)
      bf16x8 hv, lv;
      if (g == 2) {
        #pragma unroll
        for (int e = 0; e < 8; ++e) { hv[e] = 0; lv[e] = 0; }
      } else {
        const float* p = whh + (size_t)(((g == 3 ? 2 : g) * H_) + j0 + jj) * H_ + kh;
        #pragma unroll
        for (int e = 0; e < 8; ++e) {
          float v = p[e];
          uint32 hb = bf16_rne(v);
          float hf = __builtin_bit_cast(float, hb << 16);
          uint32 lb = bf16_rne(v - hf);
          hv[e] = (short)hb; lv[e] = (short)lb;
        }
      }
      rah[i] = hv; ral[i] = lv;
    }
  }

  const int ejj = tid >> 7, eb = tid & 127;
  float bir = 0.f, biz = 0.f, bin = 0.f, bhr = 0.f, bhz = 0.f, bhn = 0.f;
  if (tid < 512) {
    int j = j0 + ejj;
    bir = bih[j]; biz = bih[H_ + j]; bin = bih[2 * H_ + j];
    bhr = bhh[j]; bhz = bhh[H_ + j]; bhn = bhh[2 * H_ + j];
  }
  float hprev_r = 0.f;
  const size_t pw_off = ((((size_t)(j0 >> 5)) * 8) << 10);
  __syncthreads();

  // prologue: stage chunks 0,1 of t=0 into buf0
  stage_pair(lds, xpl, ringp, 0, 0, 0, sp, spl, snp, lane);

  for (int t = 0; t < T_; ++t) {
    f32x4 acc = {0.f, 0.f, 0.f, 0.f};

    // ---- phases 0..19: A from LDS
    #pragma unroll 4
    for (int p = 0; p < 20; ++p) {
      stage_pair(lds, xpl, ringp, p + 1, t, t, sp, spl, snp, lane);
      asm volatile("s_waitcnt vmcnt(2)" ::: "memory");
      __builtin_amdgcn_s_barrier();
      __builtin_amdgcn_sched_barrier(0);
      {
        const int c = 2 * p + cw;
        bf16x8 ah = *(const bf16x8*)(lds + (c << 10) + (lane << 4));
        bf16x8 al = *(const bf16x8*)(lds + A_LO_ + (c << 10) + (lane << 4));
        const char* bb = lds + BOFF_ + ((p & 1) << 15) + (cw << 14);
        bf16x8 bh = *(const bf16x8*)(bb + (ntc << 10) + (lane << 4));
        bf16x8 bl = *(const bf16x8*)(bb + 8192 + (ntc << 10) + (lane << 4));
        acc = __builtin_amdgcn_mfma_f32_16x16x32_bf16(ah, bh, acc, 0, 0, 0);
        acc = __builtin_amdgcn_mfma_f32_16x16x32_bf16(ah, bl, acc, 0, 0, 0);
        acc = __builtin_amdgcn_mfma_f32_16x16x32_bf16(al, bh, acc, 0, 0, 0);
      }
      __builtin_amdgcn_sched_barrier(0);
      __builtin_amdgcn_s_barrier();
    }

    // ---- phases 20..23: A from registers (static index)
    #pragma unroll
    for (int i = 0; i < 4; ++i) {
      const int p = 20 + i;
      if (p < 23) {
        stage_pair(lds, xpl, ringp, p + 1, t, t, sp, spl, snp, lane);
        asm volatile("s_waitcnt vmcnt(2)" ::: "memory");
      } else if (t < T_ - 1) {
        stage_pair(lds, xpl, ringp, 0, t + 1, t + 1, sp, spl, snp, lane);
        asm volatile("s_waitcnt vmcnt(2)" ::: "memory");
      } else {
        asm volatile("s_waitcnt vmcnt(0)" ::: "memory");
      }
      __builtin_amdgcn_s_barrier();
      __builtin_amdgcn_sched_barrier(0);
      {
        const char* bb = lds + BOFF_ + ((p & 1) << 15) + (cw << 14);
        bf16x8 bh = *(const bf16x8*)(bb + (ntc << 10) + (lane << 4));
        bf16x8 bl = *(const bf16x8*)(bb + 8192 + (ntc << 10) + (lane << 4));
        acc = __builtin_amdgcn_mfma_f32_16x16x32_bf16(rah[i], bh, acc, 0, 0, 0);
        acc = __builtin_amdgcn_mfma_f32_16x16x32_bf16(rah[i], bl, acc, 0, 0, 0);
        acc = __builtin_amdgcn_mfma_f32_16x16x32_bf16(ral[i], bh, acc, 0, 0, 0);
      }
      __builtin_amdgcn_sched_barrier(0);
      __builtin_amdgcn_s_barrier();
    }

    // ---- epilogue: dump into buf1 (buf0 holds t+1 prefetch)
    *(f32x4*)(lds + BOFF2_ + (((cw << 3) + ntc) << 10) + (lane << 4)) = acc;
    __syncthreads();

    if (tid < 512) {
      float sv[4];
      #pragma unroll
      for (int g = 0; g < 4; ++g) {
        int lr = (eb & 15) | (g << 4);
        const char* d0 = lds + BOFF2_ + (((eb >> 4)) << 10) + (lr << 4) + (ejj << 2);
        float v0 = *(const float*)d0;
        float v1 = *(const float*)(d0 + 8192);
        sv[g] = v0 + v1;
      }
      float rr = sigf(sv[0] + bir + bhr);
      float zz = sigf(sv[1] + biz + bhz);
      float nn = tanhf(sv[2] + bin + rr * (sv[3] + bhn));
      float hv = (1.f - zz) * nn + zz * hprev_r;
      hprev_r = hv;
      ((float*)(lds + BOFF2_ + 16384))[(ejj << 7) + eb] = hv;
      if (t == T_ - 1) hq[((blockIdx.x * 128 + eb) << 2) + ejj] = hv;
    }
    __syncthreads();

    if (tid < 128) {
      const int b = tid;
      const float* hl = (const float*)(lds + BOFF2_ + 16384);
      uint32 hh[4], ll[4];
      #pragma unroll
      for (int i = 0; i < 4; ++i) {
        float v = hl[(i << 7) + b];
        uint32 hb = bf16_rne(v);
        float hf = __builtin_bit_cast(float, hb << 16);
        ll[i] = bf16_rne(v - hf);
        hh[i] = hb;
      }
      u64t HI = (u64t)hh[0] | ((u64t)hh[1] << 16) | ((u64t)hh[2] << 32) | ((u64t)hh[3] << 48);
      u64t LO = (u64t)ll[0] | ((u64t)ll[1] << 16) | ((u64t)ll[2] << 32) | ((u64t)ll[3] << 48);
      int lane_w = (((j0 & 31) >> 3) << 4) | (b & 15);
      size_t byteoff = pw_off + (((size_t)(b >> 4)) << 10) + ((size_t)lane_w << 4) + ((j0 & 4) ? 8 : 0);
      char* base = ringp + (size_t)(t + 1) * 524288;
      st_u64_sc1(base + byteoff, HI);
      st_u64_sc1(base + 262144 + byteoff, LO);
    }
    gridbar(barr + t);
  }
}

// ================= r10 fallback kernel (proven) ==============================
__device__ __forceinline__ int boff(int kt, int nt, int lane) {
  return (((((kt << 3) + nt) << 6) + lane) << 4) ^ ((nt & 3) << 5);
}

__global__ __launch_bounds__(256) void xt_kernel(
    const float* __restrict__ X, float4* __restrict__ XT4)
{
  int idx = blockIdx.x * 256 + threadIdx.x;
  int b  = idx & 127;
  int kq = (idx >> 7) & 127;
  int t  = idx >> 14;
  XT4[idx] = *(const float4*)(X + ((size_t)b * T_ + t) * IN_ + kq * 4);
}

template<bool RING>
__global__ __launch_bounds__(1024, 4) void gru_mfma(
    const float4* __restrict__ XT4, const float* __restrict__ X, int use_xt,
    const float* __restrict__ wih, const float* __restrict__ whh,
    const float* __restrict__ bih, const float* __restrict__ bhh,
    float* __restrict__ ring, unsigned* __restrict__ barr)
{
  extern __shared__ char lds[];
  const int tid  = threadIdx.x;
  const int lane = tid & 63;
  const int wv   = __builtin_amdgcn_readfirstlane(tid >> 6);
  const int nt   = wv & 7;
  const int ktw  = wv >> 3;
  const int j0   = blockIdx.x << 2;

  for (int ii = tid * 2; ii < 24576; ii += 2048) {
    int r = ii / 1536, k = ii - r * 1536;
    int jj = r & 3, g = r >> 2;
    float f0, f1;
    if (k < IN_) {
      if (g == 3) { f0 = 0.f; f1 = 0.f; }
      else {
        const float* p = wih + (size_t)(((g == 2 ? 2 : g) * H_) + j0 + jj) * IN_ + k;
        f0 = p[0]; f1 = p[1];
      }
    } else {
      if (g == 2) { f0 = 0.f; f1 = 0.f; }
      else {
        const float* p = whh + (size_t)(((g == 3 ? 2 : g) * H_) + j0 + jj) * H_ + (k - IN_);
        f0 = p[0]; f1 = p[1];
      }
    }
    uint32 h, l; split2(f0, f1, h, l);
    int KT = k >> 5, k32 = k & 31;
    int ln  = r + ((k32 >> 3) << 4);
    int off = (KT << 10) + (ln << 4) + ((k32 & 7) << 1);
    *(uint32*)(lds + off)         = h;
    *(uint32*)(lds + A_LOF + off) = l;
  }

  const int ejj = tid >> 7, eb = tid & 127;
  float bir = 0.f, biz = 0.f, bin = 0.f, bhr = 0.f, bhz = 0.f, bhn = 0.f;
  if (tid < 512) {
    int j = j0 + ejj;
    bir = bih[j]; biz = bih[H_ + j]; bin = bih[2 * H_ + j];
    bhr = bhh[j]; bhz = bhh[H_ + j]; bhn = bhh[2 * H_ + j];
  }
  __syncthreads();

  const int kq_loc = tid >> 7;
  const int sb     = tid & 127;
  const int s_nt   = sb >> 4;
  const int lane_w = (sb & 15) + ((kq_loc >> 1) << 4);
  const int sub8   = (kq_loc & 1) << 3;

  for (int t = 0; t < T_; ++t) {
    const float4* __restrict__ hp4 =
        (const float4*)ring + (size_t)(RING ? t : (t & 1)) * 32768;
    float* __restrict__ hnf =
        ring + (size_t)(RING ? (t + 1) : ((t + 1) & 1)) * 131072;
    const float4* __restrict__ xt_t = XT4 + (size_t)t * 16384;

    f32x4 acc = {0.f, 0.f, 0.f, 0.f};

    #pragma unroll 1
    for (int c = 0; c < 24; ++c) {
      #pragma unroll
      for (int i = 0; i < 2; ++i) {
        int kqg = (c << 4) + kq_loc + (i << 3);
        float4 v;
        if (kqg < 128) {
          if (use_xt) v = xt_t[kqg * 128 + sb];
          else        v = *(const float4*)(X + ((size_t)sb * T_ + t) * IN_ + (kqg << 2));
        } else {
          v = RING ? hp4[(kqg - 128) * 128 + sb]
                   : ld_h4_sc1(hp4 + (kqg - 128) * 128 + sb);
        }
        uint32 h01, h23, l01, l23;
        split2(v.x, v.y, h01, l01);
        split2(v.z, v.w, h23, l23);
        int bo = boff(i, s_nt, lane_w) + sub8;
        *(uint2*)(lds + BB_HI + bo) = make_uint2(h01, h23);
        *(uint2*)(lds + BB_LO + bo) = make_uint2(l01, l23);
      }
      __syncthreads();
      {
        int KT = (c << 1) + ktw;
        bf16x8 ah = *(const bf16x8*)(lds + (KT << 10) + (lane << 4));
        bf16x8 al = *(const bf16x8*)(lds + A_LOF + (KT << 10) + (lane << 4));
        int bo = boff(ktw, nt, lane);
        bf16x8 bh = *(const bf16x8*)(lds + BB_HI + bo);
        bf16x8 bl = *(const bf16x8*)(lds + BB_LO + bo);
        acc = __builtin_amdgcn_mfma_f32_16x16x32_bf16(ah, bh, acc, 0, 0, 0);
        acc = __builtin_amdgcn_mfma_f32_16x16x32_bf16(ah, bl, acc, 0, 0, 0);
        acc = __builtin_amdgcn_mfma_f32_16x16x32_bf16(al, bh, acc, 0, 0, 0);
      }
      __syncthreads();
    }

    *(f32x4*)(lds + BB_HI + boff(ktw, nt, lane)) = acc;
    __syncthreads();
    if (tid < 512) {
      float sv[4];
      #pragma unroll
      for (int g = 0; g < 4; ++g) {
        int r  = (g << 2) + ejj;
        int lr = (eb & 15) + ((r >> 2) << 4);
        int rg = (r & 3) << 2;
        float v0 = *(const float*)(lds + BB_HI + boff(0, eb >> 4, lr) + rg);
        float v1 = *(const float*)(lds + BB_HI + boff(1, eb >> 4, lr) + rg);
        sv[g] = v0 + v1;
      }
      float rr = sigf(sv[0] + bir + bhr);
      float zz = sigf(sv[1] + biz + bhz);
      float nn = tanhf(sv[2] + bin + rr * (sv[3] + bhn));
      int hidx = ((blockIdx.x * 128 + eb) << 2) + ejj;
      float hpv;
      if (RING) hpv = ((const float*)hp4)[hidx];
      else      hpv = __hip_atomic_load(&((const float*)hp4)[hidx],
                                        __ATOMIC_RELAXED, __HIP_MEMORY_SCOPE_AGENT);
      float hv = (1.f - zz) * nn + zz * hpv;
      __hip_atomic_store(&hnf[hidx], hv, __ATOMIC_RELAXED, __HIP_MEMORY_SCOPE_AGENT);
    }
    gridbar(barr + t);
  }
}

// Final h4T -> hfin[b][k]
__global__ __launch_bounds__(256) void hfin_kernel(
    const float* __restrict__ h4, float* __restrict__ out)
{
  int idx = blockIdx.x * 256 + threadIdx.x;
  int b = idx >> 10, k = idx & 1023;
  out[idx] = h4[(((k >> 2) * 128 + b) << 2) + (k & 3)];
}

// Gating GRUs: one wave per batch, gate-per-lane, all state in regs.
__global__ __launch_bounds__(64, 1) void gating_kernel(
    const float* __restrict__ X,
    const float* __restrict__ gwih0, const float* __restrict__ gwhh0,
    const float* __restrict__ gbih0, const float* __restrict__ gbhh0,
    const float* __restrict__ gwih1, const float* __restrict__ gwhh1,
    const float* __restrict__ gbih1, const float* __restrict__ gbhh1,
    float* __restrict__ omega)
{
  const int b = blockIdx.x;
  const int g = threadIdx.x;
  const int u = g & 7;
  float wi0[GIN_] = {}, wh0[GH_] = {}, wi1[GH_] = {}, wh1[GH_] = {};
  float bi0 = 0.f, bh0 = 0.f, bi1 = 0.f, bh1 = 0.f;
  if (g < 3 * GH_) {
    #pragma unroll
    for (int i = 0; i < GIN_; ++i) wi0[i] = gwih0[g * GIN_ + i];
    #pragma unroll
    for (int k = 0; k < GH_; ++k) { wh0[k] = gwhh0[g * GH_ + k]; wi1[k] = gwih1[g * GH_ + k]; wh1[k] = gwhh1[g * GH_ + k]; }
    bi0 = gbih0[g]; bh0 = gbhh0[g]; bi1 = gbih1[g]; bh1 = gbhh1[g];
  }
  float h0[GH_] = {}, h1[GH_] = {};
  for (int t = 0; t < T_; ++t) {
    float xt[GIN_];
    #pragma unroll
    for (int i = 0; i < GIN_; ++i) xt[i] = X[((size_t)b * T_ + t) * IN_ + (IN_ - GIN_) + i];
    float px = bi0, ph = bh0;
    #pragma unroll
    for (int i = 0; i < GIN_; ++i) px = fmaf(xt[i], wi0[i], px);
    #pragma unroll
    for (int k = 0; k < GH_; ++k) ph = fmaf(h0[k], wh0[k], ph);
    float s = px + ph;
    float s_r = __shfl(s, u);
    float s_z = __shfl(s, 8 + u);
    float nval = tanhf(px + sigf(s_r) * ph);
    float zval = sigf(s_z);
    float hnew = (1.f - zval) * nval + zval * h0[u];
    #pragma unroll
    for (int k = 0; k < GH_; ++k) h0[k] = __shfl(hnew, 16 + k);
    float px1 = bi1, ph1 = bh1;
    #pragma unroll
    for (int k = 0; k < GH_; ++k) px1 = fmaf(h0[k], wi1[k], px1);
    #pragma unroll
    for (int k = 0; k < GH_; ++k) ph1 = fmaf(h1[k], wh1[k], ph1);
    float s1 = px1 + ph1;
    float s1r = __shfl(s1, u);
    float s1z = __shfl(s1, 8 + u);
    float n1 = tanhf(px1 + sigf(s1r) * ph1);
    float z1 = sigf(s1z);
    float h1new = (1.f - z1) * n1 + z1 * h1[u];
    #pragma unroll
    for (int k = 0; k < GH_; ++k) h1[k] = __shfl(h1new, 16 + k);
  }
  if (g < GH_) {
    float m = h1[0];
    #pragma unroll
    for (int k = 1; k < GH_; ++k) m = fmaxf(m, h1[k]);
    float sum = 0.f;
    #pragma unroll
    for (int k = 0; k < GH_; ++k) sum += expf(h1[k] - m);
    omega[b * GH_ + g] = expf(h1[g] - m) / sum;
  }
}

// MoE layer
__global__ __launch_bounds__(256, 2) void moe_kernel(
    const float* __restrict__ in, const float* __restrict__ w,
    const float* __restrict__ bias, const float* __restrict__ omega,
    float* __restrict__ out, int K, int act)
{
  __shared__ float4 lin4[64 * 32];
  __shared__ float  ldsw[E_ * 4 * 128];
  const int tid  = threadIdx.x;
  const int bh   = blockIdx.x & 1;
  const int jt   = blockIdx.x >> 1;
  const int wv   = tid >> 6;
  const int lane = tid & 63;
  const int j0   = jt * 4;
  const int j    = __builtin_amdgcn_readfirstlane(j0 + wv);
  const int b    = bh * 64 + lane;

  float acc[E_] = {0.f,0.f,0.f,0.f,0.f,0.f,0.f,0.f};
  const float4* row4 = &lin4[lane * 32];
  const int nch = K / 128;

  for (int c = 0; c < nch; ++c) {
    __syncthreads();
    const int k0 = c * 128;
    #pragma unroll
    for (int it = 0; it < 8; ++it) {
      int f = it * 256 + tid;
      int bb = f >> 5, q = f & 31;
      float4 v = *(const float4*)(in + (size_t)(bh * 64 + bb) * K + k0 + q * 4);
      lin4[bb * 32 + ((q & 24) | ((q ^ bb) & 7))] = v;
    }
    #pragma unroll
    for (int it = 0; it < 4; ++it) {
      int f = it * 256 + tid;
      int e = f >> 7, k = f & 127;
      float4 v = *(const float4*)(w + ((size_t)e * K + k0 + k) * HH_ + j0);
      ldsw[(e * 4 + 0) * 128 + k] = v.x;
      ldsw[(e * 4 + 1) * 128 + k] = v.y;
      ldsw[(e * 4 + 2) * 128 + k] = v.z;
      ldsw[(e * 4 + 3) * 128 + k] = v.w;
    }
    __syncthreads();
    #pragma unroll 2
    for (int q = 0; q < 32; ++q) {
      float4 xv = row4[(q & 24) | ((q ^ lane) & 7)];
      #pragma unroll
      for (int e = 0; e < E_; ++e) {
        const float4 wq = *(const float4*)&ldsw[(e * 4 + wv) * 128 + 4 * q];
        acc[e] = fmaf(xv.x, wq.x, acc[e]);
        acc[e] = fmaf(xv.y, wq.y, acc[e]);
        acc[e] = fmaf(xv.z, wq.z, acc[e]);
        acc[e] = fmaf(xv.w, wq.w, acc[e]);
      }
    }
  }

  float om[E_];
  #pragma unroll
  for (int e = 0; e < E_; ++e) om[e] = omega[b * E_ + e];
  float v = 0.f;
  #pragma unroll
  for (int e = 0; e < E_; ++e) v = fmaf(om[e], acc[e] + bias[e * HH_ + j], v);
  if (act == 0) v = (v > 0.f) ? v : expm1f(v);
  else          v = fminf(fmaxf(v, 0.f), 1.f);
  out[(size_t)b * HH_ + j] = v;
}

extern "C" void kernel_launch(void* const* d_in, const int* in_sizes, int n_in,
                              void* d_out, int out_size, void* d_ws, size_t ws_size,
                              hipStream_t stream) {
  (void)in_sizes; (void)n_in; (void)out_size;
  const float* X     = (const float*)d_in[0];
  const float* gwih0 = (const float*)d_in[1];
  const float* gwhh0 = (const float*)d_in[2];
  const float* gbih0 = (const float*)d_in[3];
  const float* gbhh0 = (const float*)d_in[4];
  const float* gwih1 = (const float*)d_in[5];
  const float* gwhh1 = (const float*)d_in[6];
  const float* gbih1 = (const float*)d_in[7];
  const float* gbhh1 = (const float*)d_in[8];
  const float* mwih  = (const float*)d_in[9];
  const float* mwhh  = (const float*)d_in[10];
  const float* mbih  = (const float*)d_in[11];
  const float* mbhh  = (const float*)d_in[12];
  const float* w1    = (const float*)d_in[13];
  const float* b1    = (const float*)d_in[14];
  const float* w2    = (const float*)d_in[15];
  const float* b2    = (const float*)d_in[16];
  const float* w3    = (const float*)d_in[17];
  const float* b3    = (const float*)d_in[18];

  const size_t HBUF = (size_t)B_ * H_;
  size_t tierS_f = 256 + HBUF + 101 * HBUF + 1024 + 2 * (size_t)B_ * HH_ + HBUF + 6553600;
  const size_t XTF = (size_t)T_ * IN_ * B_;
  size_t ringA = 256 + (size_t)(T_ + 1) * HBUF + HBUF + 1024 + 2 * (size_t)B_ * HH_ + XTF;
  size_t ringB = 256 + 2 * HBUF + HBUF + 1024 + 2 * (size_t)B_ * HH_ + XTF;

  float* ws = (float*)d_ws;

  if (ws_size >= tierS_f * sizeof(float)) {
    unsigned* barr = (unsigned*)ws;
    float* hq    = ws + 256;
    float* ringp = hq + HBUF;
    float* om    = ringp + 101 * HBUF;
    float* a1    = om + 1024;
    float* a2    = a1 + (size_t)B_ * HH_;
    float* hfin  = a2 + (size_t)B_ * HH_;
    float* xpl   = hfin + HBUF;

    (void)hipMemsetAsync(d_ws, 0, 256 * sizeof(float), stream);
    (void)hipMemsetAsync(ringp, 0, 524288, stream);
    (void)hipFuncSetAttribute((const void*)gru_mfma4,
                        hipFuncAttributeMaxDynamicSharedMemorySize, LDSZ4);

    gating_kernel<<<128, 64, 0, stream>>>(X, gwih0, gwhh0, gbih0, gbhh0,
                                          gwih1, gwhh1, gbih1, gbhh1, om);
    xsplit_kernel<<<3200, 256, 0, stream>>>(X, (char*)xpl);
    gru_mfma4<<<256, 1024, LDSZ4, stream>>>((const char*)xpl, (char*)ringp,
        mwih, mwhh, mbih, mbhh, hq, barr);
    hfin_kernel<<<512, 256, 0, stream>>>(hq, hfin);
    moe_kernel<<<256, 256, 0, stream>>>(hfin, w1, b1, om, a1, H_, 0);
    moe_kernel<<<256, 256, 0, stream>>>(a1, w2, b2, om, a2, HH_, 0);
    moe_kernel<<<256, 256, 0, stream>>>(a2, w3, b3, om, (float*)d_out, HH_, 1);
    return;
  }

  // -------- fallback: r10 proven path --------
  int tierA   = ws_size >= ringA * sizeof(float);
  int use_xt  = tierA || (ws_size >= ringB * sizeof(float));
  int R       = tierA ? (T_ + 1) : 2;

  unsigned* barr = (unsigned*)ws;
  float* ring = ws + 256;
  float* hfin = ring + (size_t)R * HBUF;
  float* om   = hfin + HBUF;
  float* a1   = om + 1024;
  float* a2   = a1 + (size_t)B_ * HH_;
  float* XT   = a2 + (size_t)B_ * HH_;

  (void)hipMemsetAsync(d_ws, 0, (256 + HBUF) * sizeof(float), stream);
  (void)hipFuncSetAttribute((const void*)gru_mfma<true>,
                      hipFuncAttributeMaxDynamicSharedMemorySize, LDSZF);
  (void)hipFuncSetAttribute((const void*)gru_mfma<false>,
                      hipFuncAttributeMaxDynamicSharedMemorySize, LDSZF);

  gating_kernel<<<128, 64, 0, stream>>>(X, gwih0, gwhh0, gbih0, gbhh0,
                                        gwih1, gwhh1, gbih1, gbhh1, om);
  if (use_xt)
    xt_kernel<<<(T_ * 128 * 128) / 256, 256, 0, stream>>>(X, (float4*)XT);

  if (tierA)
    gru_mfma<true><<<256, 1024, LDSZF, stream>>>((const float4*)XT, X, use_xt,
        mwih, mwhh, mbih, mbhh, ring, barr);
  else
    gru_mfma<false><<<256, 1024, LDSZF, stream>>>((const float4*)XT, X, use_xt,
        mwih, mwhh, mbih, mbhh, ring, barr);

  const float* hlast = ring + (size_t)(tierA ? T_ : (T_ & 1)) * HBUF;
  hfin_kernel<<<512, 256, 0, stream>>>(hlast, hfin);
  moe_kernel<<<256, 256, 0, stream>>>(hfin, w1, b1, om, a1, H_, 0);
  moe_kernel<<<256, 256, 0, stream>>>(a1, w2, b2, om, a2, HH_, 0);
  moe_kernel<<<256, 256, 0, stream>>>(a2, w3, b3, om, (float*)d_out, HH_, 1);
}

// Round 14
// 1536.742 us; speedup vs baseline: 2.3567x; 1.1439x over previous
//
#include <hip/hip_runtime.h>
#include <cmath>

#define B_   128
#define T_   100
#define IN_  512
#define H_   1024
#define E_   8
#define HH_  512
#define GIN_ 5
#define GH_  8

// ---- tierS LDS: A-lo KT0..79 = 80KB | B dbuf 2x32KB ----
#define ALO_   0
#define BOFF_  81920
#define DUMP_  114688          // = buf1
#define HL_    81920           // = buf0 (reused at epilogue)
#define LDSZ5  147456
// ---- r10 fallback LDS layout
#define A_LOF 49152
#define BB_HI 98304
#define BB_LO 114688
#define LDSZF 131072

typedef unsigned long long u64t;
typedef unsigned int uint32;
typedef __attribute__((ext_vector_type(8)))  short bf16x8;
typedef __attribute__((ext_vector_type(4)))  float f32x4;
typedef __attribute__((ext_vector_type(16))) float f32x16;

__device__ __forceinline__ float sigf(float x) { return 1.0f / (1.0f + expf(-x)); }

__device__ __forceinline__ float4 ld_h4_sc1(const float4* p) {
  const u64t* q = (const u64t*)p;
  u64t a = __hip_atomic_load(q,     __ATOMIC_RELAXED, __HIP_MEMORY_SCOPE_AGENT);
  u64t b = __hip_atomic_load(q + 1, __ATOMIC_RELAXED, __HIP_MEMORY_SCOPE_AGENT);
  union { u64t u; float2 f; } ca, cb;
  ca.u = a; cb.u = b;
  return make_float4(ca.f.x, ca.f.y, cb.f.x, cb.f.y);
}

__device__ __forceinline__ void st_u64_sc1(void* p, u64t v) {
  __hip_atomic_store((u64t*)p, v, __ATOMIC_RELAXED, __HIP_MEMORY_SCOPE_AGENT);
}

__device__ __forceinline__ void gridbar(unsigned* c) {
  __syncthreads();
  if (threadIdx.x == 0) {
    __hip_atomic_fetch_add(c, 1u, __ATOMIC_RELEASE, __HIP_MEMORY_SCOPE_AGENT);
    while (__hip_atomic_load(c, __ATOMIC_RELAXED, __HIP_MEMORY_SCOPE_AGENT) < gridDim.x) {
      __builtin_amdgcn_s_sleep(1);
    }
  }
  __syncthreads();
}

__device__ __forceinline__ uint32 bf16_rne(float f) {
  uint32 u = __builtin_bit_cast(uint32, f);
  return (u + 0x7FFFu + ((u >> 16) & 1u)) >> 16;
}

__device__ __forceinline__ void split2(float f0, float f1, uint32& h, uint32& l) {
  uint32 h0 = bf16_rne(f0), h1 = bf16_rne(f1);
  float hf0 = __builtin_bit_cast(float, h0 << 16);
  float hf1 = __builtin_bit_cast(float, h1 << 16);
  uint32 l0 = bf16_rne(f0 - hf0), l1 = bf16_rne(f1 - hf1);
  h = h0 | (h1 << 16);
  l = l0 | (l1 << 16);
}

__device__ __forceinline__ void gl_lds16(const char* g, char* l) {
  __builtin_amdgcn_global_load_lds(
      (const __attribute__((address_space(1))) uint32*)(const void*)g,
      (__attribute__((address_space(3))) uint32*)(void*)l, 16, 0, 0);
}

// ---- one-shot: X -> bf16 hi/lo planes, 32-col B-frag layout for 32x32x16
// plane layout [pl][t][KT 0..31][bq 0..3][lane*16B]; lane = col + 32*kg, e = k%8
__global__ __launch_bounds__(256) void xsplit_kernel(
    const float* __restrict__ X, char* __restrict__ xpl)
{
  int idx  = blockIdx.x * 256 + threadIdx.x;   // < 819200
  int lane = idx & 63;
  int bq   = (idx >> 6) & 3;
  int KT   = (idx >> 8) & 31;
  int t    = idx >> 13;
  int col  = lane & 31, kg = lane >> 5;
  int b    = bq * 32 + col;
  int k    = KT * 16 + kg * 8;
  const float* src = X + ((size_t)b * T_ + t) * IN_ + k;
  float4 va = *(const float4*)src;
  float4 vb = *(const float4*)(src + 4);
  uint32 h0,h1,h2,h3,l0,l1,l2,l3;
  split2(va.x, va.y, h0, l0); split2(va.z, va.w, h1, l1);
  split2(vb.x, vb.y, h2, l2); split2(vb.z, vb.w, h3, l3);
  size_t off = ((((size_t)t * 32 + KT) * 4 + bq) << 10) + ((size_t)lane << 4);
  *(uint4*)(xpl + off)            = make_uint4(h0, h1, h2, h3);
  *(uint4*)(xpl + 13107200 + off) = make_uint4(l0, l1, l2, l3);
}

// stage both planes of one (KT, nt) 1KB slice pair into B dbuf
__device__ __forceinline__ void stageS(
    char* lds, const char* xpl, const char* ringp,
    int t, int pn, int ko, int nt, int bq, int lane)
{
  const int KT = 8 * pn + ko;
  char* dst = lds + BOFF_ + ((pn & 1) << 15) + (ko << 12) + (nt << 11);
  const char *s0, *s1;
  if (KT < 32) {
    size_t o = ((((size_t)t * 32 + KT) * 4 + bq) << 10) + ((size_t)lane << 4);
    s0 = xpl + o;
    s1 = xpl + 13107200 + o;
  } else {
    size_t o = (size_t)t * 524288 + ((((size_t)(KT - 32) * 4) + bq) << 10) + ((size_t)lane << 4);
    s0 = ringp + o;
    s1 = ringp + 262144 + o;
  }
  gl_lds16(s0, dst);
  gl_lds16(s1, dst + 1024);
}

// ===== tierS persistent GRU: 32x32x16 MFMA, 12 phases/step =====
// 256 blocks x 1024 threads, 1 block/CU. Block = 8 j x 64 b (bid: jg=bid>>1, bh=bid&1).
// M=32 rows = 4 gates x 8 j. Waves = 8 k-parities (q) x 2 n-tiles (ntc).
// A-hi: 12 frags in regs. A-lo: KT0..79 LDS, KT80..95 regs. B: streamed dbuf.
__global__ __launch_bounds__(1024, 4) void gru_mfma5(
    const char* __restrict__ xpl, char* __restrict__ ringp,
    const float* __restrict__ wih, const float* __restrict__ whh,
    const float* __restrict__ bih, const float* __restrict__ bhh,
    float* __restrict__ hq, unsigned* __restrict__ barr)
{
  extern __shared__ char lds[];
  const int tid  = threadIdx.x;
  const int lane = tid & 63;
  const int wv   = __builtin_amdgcn_readfirstlane(tid >> 6);
  const int q    = wv >> 1;            // k-parity 0..7
  const int ntc  = wv & 1;             // n-tile 0..1
  const int bid  = blockIdx.x;
  const int j0   = (bid >> 1) << 3;    // 8 j-cols
  const int bhalf = bid & 1;
  const int bq   = bhalf * 2 + ntc;    // staged batch-quad

  // ---- one-time: A fragments. row r = lane&31: g=r>>3, jl=r&7. k-group = lane>>5.
  bf16x8 rah[12], ral2[2];
  {
    const int rrow = lane & 31, g = rrow >> 3, jl_a = rrow & 7, kg_a = lane >> 5;
    const int jA = j0 + jl_a;
    #pragma unroll
    for (int p = 0; p < 12; ++p) {
      const int KT = 8 * p + q;
      const int kb = KT * 16 + kg_a * 8;
      bf16x8 hi8, lo8;
      bool zero = (p <= 3) ? (g == 3) : (g == 2);
      if (zero) {
        #pragma unroll
        for (int e = 0; e < 8; ++e) { hi8[e] = 0; lo8[e] = 0; }
      } else {
        const float* srcp;
        if (p <= 3) srcp = wih + (size_t)(g * H_ + jA) * IN_ + kb;
        else        srcp = whh + (size_t)(((g == 3) ? 2 : g) * H_ + jA) * H_ + (kb - IN_);
        float4 va = *(const float4*)srcp;
        float4 vb = *(const float4*)(srcp + 4);
        float vv[8] = {va.x, va.y, va.z, va.w, vb.x, vb.y, vb.z, vb.w};
        #pragma unroll
        for (int e = 0; e < 8; ++e) {
          uint32 hb = bf16_rne(vv[e]);
          float hf = __builtin_bit_cast(float, hb << 16);
          uint32 lb = bf16_rne(vv[e] - hf);
          hi8[e] = (short)hb; lo8[e] = (short)lb;
        }
      }
      rah[p] = hi8;
      if (p <= 9) {
        if (ntc == 0)
          *(bf16x8*)(lds + ALO_ + (KT << 10) + (lane << 4)) = lo8;
      } else {
        ral2[p - 10] = lo8;
      }
    }
  }

  // epilogue mapping: thread (jl = tid>>6, b = tid&63) for tid<512
  const int ejl = tid >> 6, eb = tid & 63;
  float bir = 0.f, biz = 0.f, bin = 0.f, bhr = 0.f, bhz = 0.f, bhn = 0.f;
  if (tid < 512) {
    int j = j0 + ejl;
    bir = bih[j]; biz = bih[H_ + j]; bin = bih[2 * H_ + j];
    bhr = bhh[j]; bhz = bhh[H_ + j]; bhn = bhh[2 * H_ + j];
  }
  float hprev_r = 0.f;
  __syncthreads();

  for (int t = 0; t < T_; ++t) {
    f32x16 acc = {0.f,0.f,0.f,0.f,0.f,0.f,0.f,0.f,0.f,0.f,0.f,0.f,0.f,0.f,0.f,0.f};

    stageS(lds, xpl, ringp, t, 0, q, ntc, bq, lane);

    #pragma unroll
    for (int p = 0; p < 12; ++p) {
      if (p < 11) {
        stageS(lds, xpl, ringp, t, p + 1, q, ntc, bq, lane);
        asm volatile("s_waitcnt vmcnt(2)" ::: "memory");
      } else {
        asm volatile("s_waitcnt vmcnt(0)" ::: "memory");
      }
      __builtin_amdgcn_s_barrier();
      __builtin_amdgcn_sched_barrier(0);
      {
        const int KT = 8 * p + q;
        bf16x8 al;
        if (p < 10) al = *(const bf16x8*)(lds + ALO_ + (KT << 10) + (lane << 4));
        else        al = ral2[p - 10];
        const char* bbp = lds + BOFF_ + ((p & 1) << 15) + (q << 12) + (ntc << 11);
        bf16x8 bh = *(const bf16x8*)(bbp + (lane << 4));
        bf16x8 bl = *(const bf16x8*)(bbp + 1024 + (lane << 4));
        acc = __builtin_amdgcn_mfma_f32_32x32x16_bf16(rah[p], bh, acc, 0, 0, 0);
        acc = __builtin_amdgcn_mfma_f32_32x32x16_bf16(rah[p], bl, acc, 0, 0, 0);
        acc = __builtin_amdgcn_mfma_f32_32x32x16_bf16(al,     bh, acc, 0, 0, 0);
      }
      __builtin_amdgcn_sched_barrier(0);
      __builtin_amdgcn_s_barrier();
    }

    // ---- 2-round k-partial dump into buf1 + reduce ----
    float sv[4] = {0.f, 0.f, 0.f, 0.f};
    const int bb5 = eb >> 5, bl_ = eb & 31, jlh = ejl >> 2, jli = ejl & 3;
    const int laneoff = ((bl_ + (jlh << 5)) << 4) + (jli << 2);

    if (q < 4) {
      char* d = lds + DUMP_ + ((q & 3) << 13) + (ntc << 12) + (lane << 4);
      *(f32x4*)(d)          = (f32x4){acc[0],  acc[1],  acc[2],  acc[3]};
      *(f32x4*)(d + 1024)   = (f32x4){acc[4],  acc[5],  acc[6],  acc[7]};
      *(f32x4*)(d + 2048)   = (f32x4){acc[8],  acc[9],  acc[10], acc[11]};
      *(f32x4*)(d + 3072)   = (f32x4){acc[12], acc[13], acc[14], acc[15]};
    }
    __syncthreads();
    if (tid < 512) {
      #pragma unroll
      for (int qq = 0; qq < 4; ++qq) {
        const char* base = lds + DUMP_ + (qq << 13) + (bb5 << 12);
        #pragma unroll
        for (int g = 0; g < 4; ++g) sv[g] += *(const float*)(base + (g << 10) + laneoff);
      }
    }
    __syncthreads();
    if (q >= 4) {
      char* d = lds + DUMP_ + ((q & 3) << 13) + (ntc << 12) + (lane << 4);
      *(f32x4*)(d)          = (f32x4){acc[0],  acc[1],  acc[2],  acc[3]};
      *(f32x4*)(d + 1024)   = (f32x4){acc[4],  acc[5],  acc[6],  acc[7]};
      *(f32x4*)(d + 2048)   = (f32x4){acc[8],  acc[9],  acc[10], acc[11]};
      *(f32x4*)(d + 3072)   = (f32x4){acc[12], acc[13], acc[14], acc[15]};
    }
    __syncthreads();
    if (tid < 512) {
      #pragma unroll
      for (int qq = 0; qq < 4; ++qq) {
        const char* base = lds + DUMP_ + (qq << 13) + (bb5 << 12);
        #pragma unroll
        for (int g = 0; g < 4; ++g) sv[g] += *(const float*)(base + (g << 10) + laneoff);
      }
      float rr = sigf(sv[0] + bir + bhr);
      float zz = sigf(sv[1] + biz + bhz);
      float nn = tanhf(sv[2] + bin + rr * (sv[3] + bhn));
      float hv = (1.f - zz) * nn + zz * hprev_r;
      hprev_r = hv;
      ((float*)(lds + HL_))[(ejl << 6) + eb] = hv;
      if (t == T_ - 1) hq[(size_t)(bhalf * 64 + eb) * H_ + (j0 + ejl)] = hv;
    }
    __syncthreads();

    // ---- h-plane packer: thread b packs 8 j into one 16B frag slot per plane
    if (tid < 64) {
      const int b = tid;
      const float* hl = (const float*)(lds + HL_);
      uint32 hi16[8], lo16[8];
      #pragma unroll
      for (int jl = 0; jl < 8; ++jl) {
        float v = hl[(jl << 6) + b];
        uint32 hb = bf16_rne(v);
        float hf = __builtin_bit_cast(float, hb << 16);
        lo16[jl] = bf16_rne(v - hf);
        hi16[jl] = hb;
      }
      u64t H0 = (u64t)hi16[0] | ((u64t)hi16[1] << 16) | ((u64t)hi16[2] << 32) | ((u64t)hi16[3] << 48);
      u64t H1 = (u64t)hi16[4] | ((u64t)hi16[5] << 16) | ((u64t)hi16[6] << 32) | ((u64t)hi16[7] << 48);
      u64t L0 = (u64t)lo16[0] | ((u64t)lo16[1] << 16) | ((u64t)lo16[2] << 32) | ((u64t)lo16[3] << 48);
      u64t L1 = (u64t)lo16[4] | ((u64t)lo16[5] << 16) | ((u64t)lo16[6] << 32) | ((u64t)lo16[7] << 48);
      const int kg  = (bid >> 1) & 1;
      const int KTh = bid >> 2;
      const int bq2 = bhalf * 2 + (b >> 5);
      const int lane_f = (b & 31) + (kg << 5);
      size_t off = ((((size_t)KTh << 2) + bq2) << 10) + ((size_t)lane_f << 4);
      char* basep = ringp + (size_t)(t + 1) * 524288;
      st_u64_sc1(basep + off, H0);
      st_u64_sc1(basep + off + 8, H1);
      st_u64_sc1(basep + 262144 + off, L0);
      st_u64_sc1(basep + 262144 + off + 8, L1);
    }
    gridbar(barr + t);
  }
}

// ================= r10 fallback kernel (proven) ==============================
__device__ __forceinline__ int boff(int kt, int nt, int lane) {
  return (((((kt << 3) + nt) << 6) + lane) << 4) ^ ((nt & 3) << 5);
}

__global__ __launch_bounds__(256) void xt_kernel(
    const float* __restrict__ X, float4* __restrict__ XT4)
{
  int idx = blockIdx.x * 256 + threadIdx.x;
  int b  = idx & 127;
  int kq = (idx >> 7) & 127;
  int t  = idx >> 14;
  XT4[idx] = *(const float4*)(X + ((size_t)b * T_ + t) * IN_ + kq * 4);
}

template<bool RING>
__global__ __launch_bounds__(1024, 4) void gru_mfma(
    const float4* __restrict__ XT4, const float* __restrict__ X, int use_xt,
    const float* __restrict__ wih, const float* __restrict__ whh,
    const float* __restrict__ bih, const float* __restrict__ bhh,
    float* __restrict__ ring, unsigned* __restrict__ barr)
{
  extern __shared__ char lds[];
  const int tid  = threadIdx.x;
  const int lane = tid & 63;
  const int wv   = __builtin_amdgcn_readfirstlane(tid >> 6);
  const int nt   = wv & 7;
  const int ktw  = wv >> 3;
  const int j0   = blockIdx.x << 2;

  for (int ii = tid * 2; ii < 24576; ii += 2048) {
    int r = ii / 1536, k = ii - r * 1536;
    int jj = r & 3, g = r >> 2;
    float f0, f1;
    if (k < IN_) {
      if (g == 3) { f0 = 0.f; f1 = 0.f; }
      else {
        const float* p = wih + (size_t)(((g == 2 ? 2 : g) * H_) + j0 + jj) * IN_ + k;
        f0 = p[0]; f1 = p[1];
      }
    } else {
      if (g == 2) { f0 = 0.f; f1 = 0.f; }
      else {
        const float* p = whh + (size_t)(((g == 3 ? 2 : g) * H_) + j0 + jj) * H_ + (k - IN_);
        f0 = p[0]; f1 = p[1];
      }
    }
    uint32 h, l; split2(f0, f1, h, l);
    int KT = k >> 5, k32 = k & 31;
    int ln  = r + ((k32 >> 3) << 4);
    int off = (KT << 10) + (ln << 4) + ((k32 & 7) << 1);
    *(uint32*)(lds + off)         = h;
    *(uint32*)(lds + A_LOF + off) = l;
  }

  const int ejj = tid >> 7, eb = tid & 127;
  float bir = 0.f, biz = 0.f, bin = 0.f, bhr = 0.f, bhz = 0.f, bhn = 0.f;
  if (tid < 512) {
    int j = j0 + ejj;
    bir = bih[j]; biz = bih[H_ + j]; bin = bih[2 * H_ + j];
    bhr = bhh[j]; bhz = bhh[H_ + j]; bhn = bhh[2 * H_ + j];
  }
  __syncthreads();

  const int kq_loc = tid >> 7;
  const int sb     = tid & 127;
  const int s_nt   = sb >> 4;
  const int lane_w = (sb & 15) + ((kq_loc >> 1) << 4);
  const int sub8   = (kq_loc & 1) << 3;

  for (int t = 0; t < T_; ++t) {
    const float4* __restrict__ hp4 =
        (const float4*)ring + (size_t)(RING ? t : (t & 1)) * 32768;
    float* __restrict__ hnf =
        ring + (size_t)(RING ? (t + 1) : ((t + 1) & 1)) * 131072;
    const float4* __restrict__ xt_t = XT4 + (size_t)t * 16384;

    f32x4 acc = {0.f, 0.f, 0.f, 0.f};

    #pragma unroll 1
    for (int c = 0; c < 24; ++c) {
      #pragma unroll
      for (int i = 0; i < 2; ++i) {
        int kqg = (c << 4) + kq_loc + (i << 3);
        float4 v;
        if (kqg < 128) {
          if (use_xt) v = xt_t[kqg * 128 + sb];
          else        v = *(const float4*)(X + ((size_t)sb * T_ + t) * IN_ + (kqg << 2));
        } else {
          v = RING ? hp4[(kqg - 128) * 128 + sb]
                   : ld_h4_sc1(hp4 + (kqg - 128) * 128 + sb);
        }
        uint32 h01, h23, l01, l23;
        split2(v.x, v.y, h01, l01);
        split2(v.z, v.w, h23, l23);
        int bo = boff(i, s_nt, lane_w) + sub8;
        *(uint2*)(lds + BB_HI + bo) = make_uint2(h01, h23);
        *(uint2*)(lds + BB_LO + bo) = make_uint2(l01, l23);
      }
      __syncthreads();
      {
        int KT = (c << 1) + ktw;
        bf16x8 ah = *(const bf16x8*)(lds + (KT << 10) + (lane << 4));
        bf16x8 al = *(const bf16x8*)(lds + A_LOF + (KT << 10) + (lane << 4));
        int bo = boff(ktw, nt, lane);
        bf16x8 bh = *(const bf16x8*)(lds + BB_HI + bo);
        bf16x8 bl = *(const bf16x8*)(lds + BB_LO + bo);
        acc = __builtin_amdgcn_mfma_f32_16x16x32_bf16(ah, bh, acc, 0, 0, 0);
        acc = __builtin_amdgcn_mfma_f32_16x16x32_bf16(ah, bl, acc, 0, 0, 0);
        acc = __builtin_amdgcn_mfma_f32_16x16x32_bf16(al, bh, acc, 0, 0, 0);
      }
      __syncthreads();
    }

    *(f32x4*)(lds + BB_HI + boff(ktw, nt, lane)) = acc;
    __syncthreads();
    if (tid < 512) {
      float sv[4];
      #pragma unroll
      for (int g = 0; g < 4; ++g) {
        int r  = (g << 2) + ejj;
        int lr = (eb & 15) + ((r >> 2) << 4);
        int rg = (r & 3) << 2;
        float v0 = *(const float*)(lds + BB_HI + boff(0, eb >> 4, lr) + rg);
        float v1 = *(const float*)(lds + BB_HI + boff(1, eb >> 4, lr) + rg);
        sv[g] = v0 + v1;
      }
      float rr = sigf(sv[0] + bir + bhr);
      float zz = sigf(sv[1] + biz + bhz);
      float nn = tanhf(sv[2] + bin + rr * (sv[3] + bhn));
      int hidx = ((blockIdx.x * 128 + eb) << 2) + ejj;
      float hpv;
      if (RING) hpv = ((const float*)hp4)[hidx];
      else      hpv = __hip_atomic_load(&((const float*)hp4)[hidx],
                                        __ATOMIC_RELAXED, __HIP_MEMORY_SCOPE_AGENT);
      float hv = (1.f - zz) * nn + zz * hpv;
      __hip_atomic_store(&hnf[hidx], hv, __ATOMIC_RELAXED, __HIP_MEMORY_SCOPE_AGENT);
    }
    gridbar(barr + t);
  }
}

// Final h4T -> hfin[b][k]  (fallback path only)
__global__ __launch_bounds__(256) void hfin_kernel(
    const float* __restrict__ h4, float* __restrict__ out)
{
  int idx = blockIdx.x * 256 + threadIdx.x;
  int b = idx >> 10, k = idx & 1023;
  out[idx] = h4[(((k >> 2) * 128 + b) << 2) + (k & 3)];
}

// Gating GRUs: one wave per batch, gate-per-lane, all state in regs.
__global__ __launch_bounds__(64, 1) void gating_kernel(
    const float* __restrict__ X,
    const float* __restrict__ gwih0, const float* __restrict__ gwhh0,
    const float* __restrict__ gbih0, const float* __restrict__ gbhh0,
    const float* __restrict__ gwih1, const float* __restrict__ gwhh1,
    const float* __restrict__ gbih1, const float* __restrict__ gbhh1,
    float* __restrict__ omega)
{
  const int b = blockIdx.x;
  const int g = threadIdx.x;
  const int u = g & 7;
  float wi0[GIN_] = {}, wh0[GH_] = {}, wi1[GH_] = {}, wh1[GH_] = {};
  float bi0 = 0.f, bh0 = 0.f, bi1 = 0.f, bh1 = 0.f;
  if (g < 3 * GH_) {
    #pragma unroll
    for (int i = 0; i < GIN_; ++i) wi0[i] = gwih0[g * GIN_ + i];
    #pragma unroll
    for (int k = 0; k < GH_; ++k) { wh0[k] = gwhh0[g * GH_ + k]; wi1[k] = gwih1[g * GH_ + k]; wh1[k] = gwhh1[g * GH_ + k]; }
    bi0 = gbih0[g]; bh0 = gbhh0[g]; bi1 = gbih1[g]; bh1 = gbhh1[g];
  }
  float h0[GH_] = {}, h1[GH_] = {};
  for (int t = 0; t < T_; ++t) {
    float xt[GIN_];
    #pragma unroll
    for (int i = 0; i < GIN_; ++i) xt[i] = X[((size_t)b * T_ + t) * IN_ + (IN_ - GIN_) + i];
    float px = bi0, ph = bh0;
    #pragma unroll
    for (int i = 0; i < GIN_; ++i) px = fmaf(xt[i], wi0[i], px);
    #pragma unroll
    for (int k = 0; k < GH_; ++k) ph = fmaf(h0[k], wh0[k], ph);
    float s = px + ph;
    float s_r = __shfl(s, u);
    float s_z = __shfl(s, 8 + u);
    float nval = tanhf(px + sigf(s_r) * ph);
    float zval = sigf(s_z);
    float hnew = (1.f - zval) * nval + zval * h0[u];
    #pragma unroll
    for (int k = 0; k < GH_; ++k) h0[k] = __shfl(hnew, 16 + k);
    float px1 = bi1, ph1 = bh1;
    #pragma unroll
    for (int k = 0; k < GH_; ++k) px1 = fmaf(h0[k], wi1[k], px1);
    #pragma unroll
    for (int k = 0; k < GH_; ++k) ph1 = fmaf(h1[k], wh1[k], ph1);
    float s1 = px1 + ph1;
    float s1r = __shfl(s1, u);
    float s1z = __shfl(s1, 8 + u);
    float n1 = tanhf(px1 + sigf(s1r) * ph1);
    float z1 = sigf(s1z);
    float h1new = (1.f - z1) * n1 + z1 * h1[u];
    #pragma unroll
    for (int k = 0; k < GH_; ++k) h1[k] = __shfl(h1new, 16 + k);
  }
  if (g < GH_) {
    float m = h1[0];
    #pragma unroll
    for (int k = 1; k < GH_; ++k) m = fmaxf(m, h1[k]);
    float sum = 0.f;
    #pragma unroll
    for (int k = 0; k < GH_; ++k) sum += expf(h1[k] - m);
    omega[b * GH_ + g] = expf(h1[g] - m) / sum;
  }
}

// MoE layer
__global__ __launch_bounds__(256, 2) void moe_kernel(
    const float* __restrict__ in, const float* __restrict__ w,
    const float* __restrict__ bias, const float* __restrict__ omega,
    float* __restrict__ out, int K, int act)
{
  __shared__ float4 lin4[64 * 32];
  __shared__ float  ldsw[E_ * 4 * 128];
  const int tid  = threadIdx.x;
  const int bh   = blockIdx.x & 1;
  const int jt   = blockIdx.x >> 1;
  const int wv   = tid >> 6;
  const int lane = tid & 63;
  const int j0   = jt * 4;
  const int j    = __builtin_amdgcn_readfirstlane(j0 + wv);
  const int b    = bh * 64 + lane;

  float acc[E_] = {0.f,0.f,0.f,0.f,0.f,0.f,0.f,0.f};
  const float4* row4 = &lin4[lane * 32];
  const int nch = K / 128;

  for (int c = 0; c < nch; ++c) {
    __syncthreads();
    const int k0 = c * 128;
    #pragma unroll
    for (int it = 0; it < 8; ++it) {
      int f = it * 256 + tid;
      int bb = f >> 5, qq = f & 31;
      float4 v = *(const float4*)(in + (size_t)(bh * 64 + bb) * K + k0 + qq * 4);
      lin4[bb * 32 + ((qq & 24) | ((qq ^ bb) & 7))] = v;
    }
    #pragma unroll
    for (int it = 0; it < 4; ++it) {
      int f = it * 256 + tid;
      int e = f >> 7, k = f & 127;
      float4 v = *(const float4*)(w + ((size_t)e * K + k0 + k) * HH_ + j0);
      ldsw[(e * 4 + 0) * 128 + k] = v.x;
      ldsw[(e * 4 + 1) * 128 + k] = v.y;
      ldsw[(e * 4 + 2) * 128 + k] = v.z;
      ldsw[(e * 4 + 3) * 128 + k] = v.w;
    }
    __syncthreads();
    #pragma unroll 2
    for (int qq = 0; qq < 32; ++qq) {
      float4 xv = row4[(qq & 24) | ((qq ^ lane) & 7)];
      #pragma unroll
      for (int e = 0; e < E_; ++e) {
        const float4 wq = *(const float4*)&ldsw[(e * 4 + wv) * 128 + 4 * qq];
        acc[e] = fmaf(xv.x, wq.x, acc[e]);
        acc[e] = fmaf(xv.y, wq.y, acc[e]);
        acc[e] = fmaf(xv.z, wq.z, acc[e]);
        acc[e] = fmaf(xv.w, wq.w, acc[e]);
      }
    }
  }

  float om[E_];
  #pragma unroll
  for (int e = 0; e < E_; ++e) om[e] = omega[b * E_ + e];
  float v = 0.f;
  #pragma unroll
  for (int e = 0; e < E_; ++e) v = fmaf(om[e], acc[e] + bias[e * HH_ + j], v);
  if (act == 0) v = (v > 0.f) ? v : expm1f(v);
  else          v = fminf(fmaxf(v, 0.f), 1.f);
  out[(size_t)b * HH_ + j] = v;
}

extern "C" void kernel_launch(void* const* d_in, const int* in_sizes, int n_in,
                              void* d_out, int out_size, void* d_ws, size_t ws_size,
                              hipStream_t stream) {
  (void)in_sizes; (void)n_in; (void)out_size;
  const float* X     = (const float*)d_in[0];
  const float* gwih0 = (const float*)d_in[1];
  const float* gwhh0 = (const float*)d_in[2];
  const float* gbih0 = (const float*)d_in[3];
  const float* gbhh0 = (const float*)d_in[4];
  const float* gwih1 = (const float*)d_in[5];
  const float* gwhh1 = (const float*)d_in[6];
  const float* gbih1 = (const float*)d_in[7];
  const float* gbhh1 = (const float*)d_in[8];
  const float* mwih  = (const float*)d_in[9];
  const float* mwhh  = (const float*)d_in[10];
  const float* mbih  = (const float*)d_in[11];
  const float* mbhh  = (const float*)d_in[12];
  const float* w1    = (const float*)d_in[13];
  const float* b1    = (const float*)d_in[14];
  const float* w2    = (const float*)d_in[15];
  const float* b2    = (const float*)d_in[16];
  const float* w3    = (const float*)d_in[17];
  const float* b3    = (const float*)d_in[18];

  const size_t HBUF = (size_t)B_ * H_;
  size_t tierS_f = 256 + HBUF + 101 * HBUF + 1024 + 2 * (size_t)B_ * HH_ + HBUF + 6553600;
  const size_t XTF = (size_t)T_ * IN_ * B_;
  size_t ringA = 256 + (size_t)(T_ + 1) * HBUF + HBUF + 1024 + 2 * (size_t)B_ * HH_ + XTF;
  size_t ringB = 256 + 2 * HBUF + HBUF + 1024 + 2 * (size_t)B_ * HH_ + XTF;

  float* ws = (float*)d_ws;

  if (ws_size >= tierS_f * sizeof(float)) {
    unsigned* barr = (unsigned*)ws;
    float* hq    = ws + 256;
    float* ringp = hq + HBUF;
    float* om    = ringp + 101 * HBUF;
    float* a1    = om + 1024;
    float* a2    = a1 + (size_t)B_ * HH_;
    float* xpl   = a2 + (size_t)B_ * HH_ + HBUF;   // (hfin slot unused)

    (void)hipMemsetAsync(d_ws, 0, 256 * sizeof(float), stream);
    (void)hipMemsetAsync(ringp, 0, 524288, stream);
    (void)hipFuncSetAttribute((const void*)gru_mfma5,
                        hipFuncAttributeMaxDynamicSharedMemorySize, LDSZ5);

    gating_kernel<<<128, 64, 0, stream>>>(X, gwih0, gwhh0, gbih0, gbhh0,
                                          gwih1, gwhh1, gbih1, gbhh1, om);
    xsplit_kernel<<<3200, 256, 0, stream>>>(X, (char*)xpl);
    gru_mfma5<<<256, 1024, LDSZ5, stream>>>((const char*)xpl, (char*)ringp,
        mwih, mwhh, mbih, mbhh, hq, barr);
    moe_kernel<<<256, 256, 0, stream>>>(hq, w1, b1, om, a1, H_, 0);
    moe_kernel<<<256, 256, 0, stream>>>(a1, w2, b2, om, a2, HH_, 0);
    moe_kernel<<<256, 256, 0, stream>>>(a2, w3, b3, om, (float*)d_out, HH_, 1);
    return;
  }

  // -------- fallback: r10 proven path --------
  int tierA   = ws_size >= ringA * sizeof(float);
  int use_xt  = tierA || (ws_size >= ringB * sizeof(float));
  int R       = tierA ? (T_ + 1) : 2;

  unsigned* barr = (unsigned*)ws;
  float* ring = ws + 256;
  float* hfin = ring + (size_t)R * HBUF;
  float* om   = hfin + HBUF;
  float* a1   = om + 1024;
  float* a2   = a1 + (size_t)B_ * HH_;
  float* XT   = a2 + (size_t)B_ * HH_;

  (void)hipMemsetAsync(d_ws, 0, (256 + HBUF) * sizeof(float), stream);
  (void)hipFuncSetAttribute((const void*)gru_mfma<true>,
                      hipFuncAttributeMaxDynamicSharedMemorySize, LDSZF);
  (void)hipFuncSetAttribute((const void*)gru_mfma<false>,
                      hipFuncAttributeMaxDynamicSharedMemorySize, LDSZF);

  gating_kernel<<<128, 64, 0, stream>>>(X, gwih0, gwhh0, gbih0, gbhh0,
                                        gwih1, gwhh1, gbih1, gbhh1, om);
  if (use_xt)
    xt_kernel<<<(T_ * 128 * 128) / 256, 256, 0, stream>>>(X, (float4*)XT);

  if (tierA)
    gru_mfma<true><<<256, 1024, LDSZF, stream>>>((const float4*)XT, X, use_xt,
        mwih, mwhh, mbih, mbhh, ring, barr);
  else
    gru_mfma<false><<<256, 1024, LDSZF, stream>>>((const float4*)XT, X, use_xt,
        mwih, mwhh, mbih, mbhh, ring, barr);

  const float* hlast = ring + (size_t)(tierA ? T_ : (T_ & 1)) * HBUF;
  hfin_kernel<<<512, 256, 0, stream>>>(hlast, hfin);
  moe_kernel<<<256, 256, 0, stream>>>(hfin, w1, b1, om, a1, H_, 0);
  moe_kernel<<<256, 256, 0, stream>>>(a1, w2, b2, om, a2, HH_, 0);
  moe_kernel<<<256, 256, 0, stream>>>(a2, w3, b3, om, (float*)d_out, HH_, 1);
}